// Round 3
// baseline (3388.778 us; speedup 1.0000x reference)
//
#include <hip/hip_runtime.h>

#define DEV __device__ __forceinline__
typedef __attribute__((ext_vector_type(8))) short s16x8;
typedef __attribute__((ext_vector_type(4))) float f32x4;
typedef unsigned short u16;

// ---------- constants ----------
#define NB 16      // B
#define TPN 2
#define NODES 8192
#define D 128
#define P 256
#define NPS 32
#define OUT_LEN 12

DEV f32x4 mfma16(s16x8 a, s16x8 b, f32x4 c) {
  return __builtin_amdgcn_mfma_f32_16x16x32_bf16(a, b, c, 0, 0, 0);
}

DEV short f2bf(float f) {
  union { float f; unsigned u; } v; v.f = f;
  unsigned r = v.u + 0x7fffu + ((v.u >> 16) & 1u);
  return (short)(r >> 16);
}

// swizzled LDS addressing: 256B-row and 512B-row buffers, XOR bits 4-6 by row&7
DEV int swz256(int row, int b) { return (row << 8) + (b ^ ((row & 7) << 4)); }
DEV int swz512(int row, int b) { return (row << 9) + (b ^ ((row & 7) << 4)); }

// A-fragment load: lane l -> row = mbase+(l&15), k = kbase+(l>>4)*8 .. +8
DEV s16x8 ldsA(const char* base, int mbase, int kbase, int lane) {
  int row = mbase + (lane & 15);
  int b = (kbase + ((lane >> 4) << 3)) << 1;
  return *(const s16x8*)(base + swz256(row, b));
}

// butterfly reduce across lane bits 0..3 (16-lane row groups)
DEV float rowred(float v) {
  v += __shfl_xor(v, 1);
  v += __shfl_xor(v, 2);
  v += __shfl_xor(v, 4);
  v += __shfl_xor(v, 8);
  return v;
}

// ---------------- weight prep: f32 [3][K][N] -> bf16 [3][N][K] ----------------
__global__ void k_prep(const float* __restrict__ src, u16* __restrict__ dst, int K, int N) {
  int idx = blockIdx.x * 256 + threadIdx.x;
  int total = 3 * K * N;
  if (idx >= total) return;
  int l = idx / (K * N);
  int r = idx - l * K * N;
  int n = r / K;
  int k = r - n * K;
  dst[idx] = (u16)f2bf(src[l * K * N + k * N + n]);
}

// ---------------- embedding (scatter form: coalesced reads, 512B row writes) ----------------
__global__ __launch_bounds__(256) void k_embed(
    const float* __restrict__ x, const int* __restrict__ te, const int* __restrict__ reo_parts,
    const float* __restrict__ w_st, const float* __restrict__ b_st,
    const float* __restrict__ node_emb, const float* __restrict__ tod_emb,
    const float* __restrict__ dow_emb, float* __restrict__ rex) {
  __shared__ float sx[12][16], s0[12][16], s1[12][16];
  __shared__ int sed[2][16];
  __shared__ int sj[16];
  __shared__ float hb[16][132];  // pitch 132 floats to spread banks
  int gid = blockIdx.x;
  int chunk = gid & 511, bt = gid >> 9;
  int b = bt >> 1, tt = bt & 1;
  int tid = threadIdx.x;
  int nl = tid & 15, c = tid >> 4;
  int n = chunk * 16 + nl;
  if (c < 12) {
    size_t off = ((size_t)(b * 24 + tt * 12 + c)) * NODES + n;
    sx[c][nl] = x[off];
    int2 t2 = *(const int2*)(te + 2 * off);
    s0[c][nl] = (float)t2.x * (1.0f / 288.0f);
    s1[c][nl] = (float)t2.y * (1.0f / 7.0f);
  } else if (c == 12) {
    size_t off = ((size_t)(b * 24 + 22 + tt)) * NODES + n;
    int2 t2 = *(const int2*)(te + 2 * off);
    sed[0][nl] = t2.x;
    sed[1][nl] = t2.y;
  } else if (c == 13) {
    sj[nl] = reo_parts[n];
  }
  __syncthreads();
  // compute d-block c for node nl
  int db = c * 8;
  float o[8];
#pragma unroll
  for (int dd = 0; dd < 8; ++dd) {
    int d = db + dd;
    float v;
    if (d < 64) {
      float acc = b_st[d];
      const float* wd = w_st + d * 36;
#pragma unroll
      for (int p = 0; p < 12; ++p)
        acc += sx[p][nl] * wd[p] + s0[p][nl] * wd[12 + p] + s1[p][nl] * wd[24 + p];
      v = acc;
    } else if (d < 80) {
      v = tod_emb[sed[0][nl] * 16 + (d - 64)];
    } else if (d < 96) {
      v = dow_emb[sed[1][nl] * 16 + (d - 80)];
    } else {
      v = node_emb[n * 32 + (d - 96)];
    }
    o[dd] = v;
  }
  *(float4*)&hb[nl][db] = make_float4(o[0], o[1], o[2], o[3]);
  *(float4*)&hb[nl][db + 4] = make_float4(o[4], o[5], o[6], o[7]);
  __syncthreads();
  // write phase: 16 lanes sweep one row (512B contiguous)
  int row = tid >> 4, cw = tid & 15;
  float4 v0 = *(float4*)&hb[row][cw * 8];
  float4 v1 = *(float4*)&hb[row][cw * 8 + 4];
  float* dst = rex + ((size_t)bt * NODES + sj[row]) * D + cw * 8;
  *(float4*)dst = v0;
  *(float4*)(dst + 4) = v1;
}

// ---------------- fused spatial attention + MLP: 2 waves per 32-token patch ----------------
__global__ __launch_bounds__(128, 3) void k_spatial_mlp(
    float* __restrict__ rex,
    const u16* __restrict__ wqkv, const float* __restrict__ bqkv,
    const u16* __restrict__ wprj, const float* __restrict__ bprj,
    const u16* __restrict__ w1t, const float* __restrict__ b1,
    const u16* __restrict__ w2t, const float* __restrict__ b2) {
  __shared__ __align__(16) char sm[26624];
  char* Xb = sm;             // 32 x 256B swz (LN'd X / Q / AV / h1)
  char* Kb = sm + 8192;      // 32 x 256B swz (K / P / LN2'd X)
  char* VT = sm + 16384;     // 128 rows x 80B (V transposed)
  int tid = threadIdx.x;
  int w = tid >> 6, lane = tid & 63;
  int r = lane & 15, g = lane >> 4;
  float* X = rex + (size_t)blockIdx.x * (NPS * D);

  // ---- load X tile in C-layout registers: xreg[nt][e] = X[w*16+g*4+e][nt*16+r]
  float xreg[8][4];
#pragma unroll
  for (int nt = 0; nt < 8; ++nt)
#pragma unroll
    for (int e = 0; e < 4; ++e)
      xreg[nt][e] = X[(w * 16 + g * 4 + e) * D + nt * 16 + r];

  // ---- LN1 in-register
  float mn[4], rs[4];
#pragma unroll
  for (int e = 0; e < 4; ++e) {
    float s = 0.f, s2 = 0.f;
#pragma unroll
    for (int nt = 0; nt < 8; ++nt) { float v = xreg[nt][e]; s += v; s2 += v * v; }
    s = rowred(s); s2 = rowred(s2);
    float m = s * 0.0078125f;
    mn[e] = m;
    rs[e] = rsqrtf(s2 * 0.0078125f - m * m + 1e-6f);
  }
#pragma unroll
  for (int nt = 0; nt < 8; ++nt)
#pragma unroll
    for (int e = 0; e < 4; ++e)
      *(u16*)(Xb + swz256(w * 16 + g * 4 + e, (nt * 16 + r) * 2)) =
          (u16)f2bf((xreg[nt][e] - mn[e]) * rs[e]);
  s16x8 ax[4];
#pragma unroll
  for (int kt = 0; kt < 4; ++kt) ax[kt] = ldsA(Xb, w * 16, kt * 32, lane);

  // ---- QKV GEMM for own 16 tokens; Q->Xb (alias), K->Kb, V->VT
  for (int nt = 0; nt < 24; ++nt) {
    int n = nt * 16 + r;
    f32x4 a0 = {0.f, 0.f, 0.f, 0.f};
#pragma unroll
    for (int kt = 0; kt < 4; ++kt) {
      s16x8 b = *(const s16x8*)(wqkv + (size_t)n * D + kt * 32 + g * 8);
      a0 = mfma16(ax[kt], b, a0);
    }
    float bias = bqkv[n];
#pragma unroll
    for (int e = 0; e < 4; ++e) {
      float v0 = a0[e] + bias;
      int t0 = w * 16 + g * 4 + e;
      if (nt < 8) {
        *(u16*)(Xb + swz256(t0, n * 2)) = (u16)f2bf(v0);
      } else if (nt < 16) {
        *(u16*)(Kb + swz256(t0, (n - 128) * 2)) = (u16)f2bf(v0);
      } else {
        *(u16*)(VT + (n - 256) * 80 + t0 * 2) = (u16)f2bf(v0);
      }
    }
  }
  __syncthreads();

  // ---- scores: own 16 q-rows vs all 32 keys
  s16x8 aqf[4];
#pragma unroll
  for (int kt = 0; kt < 4; ++kt) aqf[kt] = ldsA(Xb, w * 16, kt * 32, lane);
  const float scale = 0.08838834764831845f;
  f32x4 sc[2];
#pragma unroll
  for (int nt2 = 0; nt2 < 2; ++nt2) {
    f32x4 acc = {0.f, 0.f, 0.f, 0.f};
#pragma unroll
    for (int kt = 0; kt < 4; ++kt) {
      s16x8 b = ldsA(Kb, nt2 * 16, kt * 32, lane);
      acc = mfma16(aqf[kt], b, acc);
    }
    sc[nt2] = acc * scale;
  }
  __syncthreads();  // all waves done reading K before P overwrites Kb

  // ---- softmax -> P into Kb (own rows)
#pragma unroll
  for (int e = 0; e < 4; ++e) {
    float v0 = sc[0][e], v1 = sc[1][e];
    float m = fmaxf(v0, v1);
    m = fmaxf(m, __shfl_xor(m, 1));
    m = fmaxf(m, __shfl_xor(m, 2));
    m = fmaxf(m, __shfl_xor(m, 4));
    m = fmaxf(m, __shfl_xor(m, 8));
    float p0 = __expf(v0 - m), p1 = __expf(v1 - m);
    float s = p0 + p1;
    s += __shfl_xor(s, 1);
    s += __shfl_xor(s, 2);
    s += __shfl_xor(s, 4);
    s += __shfl_xor(s, 8);
    float ri = 1.0f / s;
    int row = w * 16 + g * 4 + e;
    *(u16*)(Kb + swz256(row, r * 2)) = (u16)f2bf(p0 * ri);
    *(u16*)(Kb + swz256(row, (16 + r) * 2)) = (u16)f2bf(p1 * ri);
  }

  // ---- AV (K=32) -> Xb own rows
  {
    s16x8 af = ldsA(Kb, w * 16, 0, lane);
#pragma unroll
    for (int nt = 0; nt < 8; ++nt) {
      s16x8 bv = *(const s16x8*)(VT + (nt * 16 + r) * 80 + g * 16);
      f32x4 acc = {0.f, 0.f, 0.f, 0.f};
      acc = mfma16(af, bv, acc);
#pragma unroll
      for (int e = 0; e < 4; ++e)
        *(u16*)(Xb + swz256(w * 16 + g * 4 + e, (nt * 16 + r) * 2)) = (u16)f2bf(acc[e]);
    }
  }

  // ---- proj + residual in-register
  s16x8 aav[4];
#pragma unroll
  for (int kt = 0; kt < 4; ++kt) aav[kt] = ldsA(Xb, w * 16, kt * 32, lane);
#pragma unroll
  for (int nt = 0; nt < 8; ++nt) {
    int n = nt * 16 + r;
    f32x4 a0 = {0.f, 0.f, 0.f, 0.f};
#pragma unroll
    for (int kt = 0; kt < 4; ++kt) {
      s16x8 b = *(const s16x8*)(wprj + (size_t)n * D + kt * 32 + g * 8);
      a0 = mfma16(aav[kt], b, a0);
    }
    float bias = bprj[n];
#pragma unroll
    for (int e = 0; e < 4; ++e) xreg[nt][e] += a0[e] + bias;
  }

  // ---- LN2 in-register -> Kb own rows
#pragma unroll
  for (int e = 0; e < 4; ++e) {
    float s = 0.f, s2 = 0.f;
#pragma unroll
    for (int nt = 0; nt < 8; ++nt) { float v = xreg[nt][e]; s += v; s2 += v * v; }
    s = rowred(s); s2 = rowred(s2);
    float m = s * 0.0078125f;
    mn[e] = m;
    rs[e] = rsqrtf(s2 * 0.0078125f - m * m + 1e-6f);
  }
#pragma unroll
  for (int nt = 0; nt < 8; ++nt)
#pragma unroll
    for (int e = 0; e < 4; ++e)
      *(u16*)(Kb + swz256(w * 16 + g * 4 + e, (nt * 16 + r) * 2)) =
          (u16)f2bf((xreg[nt][e] - mn[e]) * rs[e]);
  s16x8 ah[4];
#pragma unroll
  for (int kt = 0; kt < 4; ++kt) ah[kt] = ldsA(Kb, w * 16, kt * 32, lane);

  // ---- fc1 + gelu -> Xb own rows
#pragma unroll
  for (int nt = 0; nt < 8; ++nt) {
    int n = nt * 16 + r;
    f32x4 a0 = {0.f, 0.f, 0.f, 0.f};
#pragma unroll
    for (int kt = 0; kt < 4; ++kt) {
      s16x8 b = *(const s16x8*)(w1t + (size_t)n * D + kt * 32 + g * 8);
      a0 = mfma16(ah[kt], b, a0);
    }
    float bias = b1[n];
#pragma unroll
    for (int e = 0; e < 4; ++e) {
      float v0 = a0[e] + bias;
      v0 = 0.5f * v0 * (1.0f + erff(v0 * 0.70710678118654752f));
      *(u16*)(Xb + swz256(w * 16 + g * 4 + e, n * 2)) = (u16)f2bf(v0);
    }
  }
  s16x8 ah2[4];
#pragma unroll
  for (int kt = 0; kt < 4; ++kt) ah2[kt] = ldsA(Xb, w * 16, kt * 32, lane);

  // ---- fc2 + residual, store X
#pragma unroll
  for (int nt = 0; nt < 8; ++nt) {
    int n = nt * 16 + r;
    f32x4 a0 = {0.f, 0.f, 0.f, 0.f};
#pragma unroll
    for (int kt = 0; kt < 4; ++kt) {
      s16x8 b = *(const s16x8*)(w2t + (size_t)n * D + kt * 32 + g * 8);
      a0 = mfma16(ah2[kt], b, a0);
    }
    float bias = b2[n];
#pragma unroll
    for (int e = 0; e < 4; ++e) xreg[nt][e] += a0[e] + bias;
  }
#pragma unroll
  for (int nt = 0; nt < 8; ++nt)
#pragma unroll
    for (int e = 0; e < 4; ++e)
      X[(w * 16 + g * 4 + e) * D + nt * 16 + r] = xreg[nt][e];
}

// ---------------- fused cross attention + MLP: 8 waves per 256-token sequence ----------------
__global__ __launch_bounds__(512) void k_cross_mlp(
    float* __restrict__ rex,
    const u16* __restrict__ wqkv, const float* __restrict__ bqkv,
    const u16* __restrict__ wprj, const float* __restrict__ bprj,
    const u16* __restrict__ w1t, const float* __restrict__ b1,
    const u16* __restrict__ w2t, const float* __restrict__ b2) {
  __shared__ __align__(16) char sm[163840];
  char* Kb = sm;            // 256 x 256B swz
  char* VT = sm + 65536;    // 128 x 512B swz (V transposed)
  int tid = threadIdx.x;
  int w = tid >> 6, lane = tid & 63;
  char* scr = sm + 131072 + w * 4096;  // per-wave 16 x 256B swz scratch
  int r = lane & 15, g = lane >> 4;

  int sq = blockIdx.x;
  int bt = sq >> 5, i = sq & 31;
  float* X0 = rex + (size_t)bt * (NODES * D) + i * D;
  const int TS = NPS * D;  // token stride = 4096 floats

  // ---- load 32 own tokens in C-layout: xreg[mt][nt][e] = X[w*32+mt*16+g*4+e][nt*16+r]
  float xreg[2][8][4];
#pragma unroll
  for (int mt = 0; mt < 2; ++mt)
#pragma unroll
    for (int nt = 0; nt < 8; ++nt)
#pragma unroll
      for (int e = 0; e < 4; ++e)
        xreg[mt][nt][e] = X0[(size_t)(w * 32 + mt * 16 + g * 4 + e) * TS + nt * 16 + r];

  // ---- LN1 in-register; build ax via wave-private scr
  s16x8 ax[2][4];
  float mn1[2][4], rs1[2][4];
#pragma unroll
  for (int mt = 0; mt < 2; ++mt) {
#pragma unroll
    for (int e = 0; e < 4; ++e) {
      float s = 0.f, s2 = 0.f;
#pragma unroll
      for (int nt = 0; nt < 8; ++nt) { float v = xreg[mt][nt][e]; s += v; s2 += v * v; }
      s = rowred(s); s2 = rowred(s2);
      float m = s * 0.0078125f;
      mn1[mt][e] = m;
      rs1[mt][e] = rsqrtf(s2 * 0.0078125f - m * m + 1e-6f);
    }
#pragma unroll
    for (int nt = 0; nt < 8; ++nt)
#pragma unroll
      for (int e = 0; e < 4; ++e)
        *(u16*)(scr + swz256(g * 4 + e, (nt * 16 + r) * 2)) =
            (u16)f2bf((xreg[mt][nt][e] - mn1[mt][e]) * rs1[mt][e]);
#pragma unroll
    for (int kt = 0; kt < 4; ++kt) ax[mt][kt] = ldsA(scr, 0, kt * 32, lane);
  }

  // ---- K,V for own tokens -> shared LDS
  for (int nt = 0; nt < 16; ++nt) {
    int n = 128 + nt * 16 + r;
    f32x4 acc[2];
#pragma unroll
    for (int mt = 0; mt < 2; ++mt) acc[mt] = (f32x4){0.f, 0.f, 0.f, 0.f};
#pragma unroll
    for (int kt = 0; kt < 4; ++kt) {
      s16x8 b = *(const s16x8*)(wqkv + (size_t)n * D + kt * 32 + g * 8);
#pragma unroll
      for (int mt = 0; mt < 2; ++mt) acc[mt] = mfma16(ax[mt][kt], b, acc[mt]);
    }
    float bias = bqkv[n];
#pragma unroll
    for (int mt = 0; mt < 2; ++mt)
#pragma unroll
      for (int e = 0; e < 4; ++e) {
        int tok = w * 32 + mt * 16 + g * 4 + e;
        float v = acc[mt][e] + bias;
        if (nt < 8)
          *(u16*)(Kb + swz256(tok, (nt * 16 + r) * 2)) = (u16)f2bf(v);
        else
          *(u16*)(VT + swz512((nt - 8) * 16 + r, tok * 2)) = (u16)f2bf(v);
      }
  }
  __syncthreads();

  const float scale = 0.08838834764831845f;
#pragma unroll
  for (int mt = 0; mt < 2; ++mt) {
    // ---- Q tile -> scr -> aq
    for (int nt = 0; nt < 8; ++nt) {
      int n = nt * 16 + r;
      f32x4 acc = {0.f, 0.f, 0.f, 0.f};
#pragma unroll
      for (int kt = 0; kt < 4; ++kt) {
        s16x8 b = *(const s16x8*)(wqkv + (size_t)n * D + kt * 32 + g * 8);
        acc = mfma16(ax[mt][kt], b, acc);
      }
      float bias = bqkv[n];
#pragma unroll
      for (int e = 0; e < 4; ++e)
        *(u16*)(scr + swz256(g * 4 + e, n * 2)) = (u16)f2bf(acc[e] + bias);
    }
    s16x8 aq[4];
#pragma unroll
    for (int kt = 0; kt < 4; ++kt) aq[kt] = ldsA(scr, 0, kt * 32, lane);

    // ---- scores vs all 256 keys (registers)
    f32x4 sc[16];
#pragma unroll
    for (int nt2 = 0; nt2 < 16; ++nt2) {
      f32x4 acc = {0.f, 0.f, 0.f, 0.f};
#pragma unroll
      for (int kt = 0; kt < 4; ++kt) {
        s16x8 b = ldsA(Kb, nt2 * 16, kt * 32, lane);
        acc = mfma16(aq[kt], b, acc);
      }
      sc[nt2] = acc * scale;
    }

    // ---- softmax
    float rinv[4];
#pragma unroll
    for (int e = 0; e < 4; ++e) {
      float m = sc[0][e];
#pragma unroll
      for (int nt2 = 1; nt2 < 16; ++nt2) m = fmaxf(m, sc[nt2][e]);
      m = fmaxf(m, __shfl_xor(m, 1));
      m = fmaxf(m, __shfl_xor(m, 2));
      m = fmaxf(m, __shfl_xor(m, 4));
      m = fmaxf(m, __shfl_xor(m, 8));
      float s = 0.f;
#pragma unroll
      for (int nt2 = 0; nt2 < 16; ++nt2) {
        float p = __expf(sc[nt2][e] - m);
        sc[nt2][e] = p;
        s += p;
      }
      s += __shfl_xor(s, 1);
      s += __shfl_xor(s, 2);
      s += __shfl_xor(s, 4);
      s += __shfl_xor(s, 8);
      rinv[e] = 1.0f / s;
    }

    // ---- AV in two key-halves via scr
    f32x4 av[8];
#pragma unroll
    for (int nt = 0; nt < 8; ++nt) av[nt] = (f32x4){0.f, 0.f, 0.f, 0.f};
#pragma unroll
    for (int h = 0; h < 2; ++h) {
#pragma unroll
      for (int nt2 = 0; nt2 < 8; ++nt2)
#pragma unroll
        for (int e = 0; e < 4; ++e)
          *(u16*)(scr + swz256(g * 4 + e, (nt2 * 16 + r) * 2)) = (u16)f2bf(sc[h * 8 + nt2][e]);
#pragma unroll
      for (int kk = 0; kk < 4; ++kk) {
        s16x8 ap = ldsA(scr, 0, kk * 32, lane);
#pragma unroll
        for (int nt = 0; nt < 8; ++nt) {
          s16x8 bv = *(const s16x8*)(VT + swz512(nt * 16 + r, (h * 128 + kk * 32 + g * 8) * 2));
          av[nt] = mfma16(ap, bv, av[nt]);
        }
      }
    }

    // ---- normalize, redistribute, proj + residual in-register
#pragma unroll
    for (int nt = 0; nt < 8; ++nt)
#pragma unroll
      for (int e = 0; e < 4; ++e)
        *(u16*)(scr + swz256(g * 4 + e, (nt * 16 + r) * 2)) = (u16)f2bf(av[nt][e] * rinv[e]);
    s16x8 aav[4];
#pragma unroll
    for (int kt = 0; kt < 4; ++kt) aav[kt] = ldsA(scr, 0, kt * 32, lane);
    for (int nt = 0; nt < 8; ++nt) {
      int n = nt * 16 + r;
      f32x4 acc = {0.f, 0.f, 0.f, 0.f};
#pragma unroll
      for (int kt = 0; kt < 4; ++kt) {
        s16x8 b = *(const s16x8*)(wprj + (size_t)n * D + kt * 32 + g * 8);
        acc = mfma16(aav[kt], b, acc);
      }
      float bias = bprj[n];
#pragma unroll
      for (int e = 0; e < 4; ++e) xreg[mt][nt][e] += acc[e] + bias;
    }

    // ---- fused MLP for this 16-row tile
    float mn2[4], rs2[4];
#pragma unroll
    for (int e = 0; e < 4; ++e) {
      float s = 0.f, s2 = 0.f;
#pragma unroll
      for (int nt = 0; nt < 8; ++nt) { float v = xreg[mt][nt][e]; s += v; s2 += v * v; }
      s = rowred(s); s2 = rowred(s2);
      float m = s * 0.0078125f;
      mn2[e] = m;
      rs2[e] = rsqrtf(s2 * 0.0078125f - m * m + 1e-6f);
    }
#pragma unroll
    for (int nt = 0; nt < 8; ++nt)
#pragma unroll
      for (int e = 0; e < 4; ++e)
        *(u16*)(scr + swz256(g * 4 + e, (nt * 16 + r) * 2)) =
            (u16)f2bf((xreg[mt][nt][e] - mn2[e]) * rs2[e]);
    s16x8 ah[4];
#pragma unroll
    for (int kt = 0; kt < 4; ++kt) ah[kt] = ldsA(scr, 0, kt * 32, lane);
#pragma unroll
    for (int nt = 0; nt < 8; ++nt) {
      int n = nt * 16 + r;
      f32x4 acc = {0.f, 0.f, 0.f, 0.f};
#pragma unroll
      for (int kt = 0; kt < 4; ++kt) {
        s16x8 b = *(const s16x8*)(w1t + (size_t)n * D + kt * 32 + g * 8);
        acc = mfma16(ah[kt], b, acc);
      }
      float bias = b1[n];
#pragma unroll
      for (int e = 0; e < 4; ++e) {
        float v0 = acc[e] + bias;
        v0 = 0.5f * v0 * (1.0f + erff(v0 * 0.70710678118654752f));
        *(u16*)(scr + swz256(g * 4 + e, n * 2)) = (u16)f2bf(v0);
      }
    }
    s16x8 ah2[4];
#pragma unroll
    for (int kt = 0; kt < 4; ++kt) ah2[kt] = ldsA(scr, 0, kt * 32, lane);
#pragma unroll
    for (int nt = 0; nt < 8; ++nt) {
      int n = nt * 16 + r;
      f32x4 acc = {0.f, 0.f, 0.f, 0.f};
#pragma unroll
      for (int kt = 0; kt < 4; ++kt) {
        s16x8 b = *(const s16x8*)(w2t + (size_t)n * D + kt * 32 + g * 8);
        acc = mfma16(ah2[kt], b, acc);
      }
      float bias = b2[n];
#pragma unroll
      for (int e = 0; e < 4; ++e) xreg[mt][nt][e] += acc[e] + bias;
    }

    // ---- store this tile
#pragma unroll
    for (int nt = 0; nt < 8; ++nt)
#pragma unroll
      for (int e = 0; e < 4; ++e)
        X0[(size_t)(w * 32 + mt * 16 + g * 4 + e) * TS + nt * 16 + r] = xreg[mt][nt][e];
  }
}

// ---------------- readout ----------------
__global__ __launch_bounds__(256) void k_readout(
    const float* __restrict__ rex, const int* __restrict__ ori_idx,
    const int* __restrict__ reo_idx, const float* __restrict__ w_reg,
    const float* __restrict__ b_reg, float* __restrict__ out) {
  __shared__ float wl[3072];
  for (int i2 = threadIdx.x; i2 < 3072; i2 += 256) wl[i2] = w_reg[i2];
  __syncthreads();
  int b = blockIdx.x >> 7;
  int chunk = blockIdx.x & 127;
  int m = chunk * 64 + (threadIdx.x >> 2);
  int q = threadIdx.x & 3;
  int nOut = ori_idx[m];
  int j = reo_idx[m];
  int t = q >> 1;
  const float* src = rex + ((size_t)(b * 2 + t) * NODES + j) * D + (q & 1) * 64;
  float acc[12] = {0.f, 0.f, 0.f, 0.f, 0.f, 0.f, 0.f, 0.f, 0.f, 0.f, 0.f, 0.f};
#pragma unroll
  for (int k = 0; k < 64; k += 4) {
    float4 v = *(const float4*)(src + k);
#pragma unroll
    for (int o = 0; o < 12; ++o) {
      float4 wv = *(const float4*)(&wl[o * 256 + q * 64 + k]);
      acc[o] += v.x * wv.x + v.y * wv.y + v.z * wv.z + v.w * wv.w;
    }
  }
#pragma unroll
  for (int o = 0; o < 12; ++o) {
    acc[o] += __shfl_xor(acc[o], 1);
    acc[o] += __shfl_xor(acc[o], 2);
  }
  if (q == 0) {
#pragma unroll
    for (int o = 0; o < 12; ++o)
      out[((size_t)b * 12 + o) * NODES + nOut] = acc[o] + b_reg[o];
  }
}

// ---------------- host ----------------
extern "C" void kernel_launch(void* const* d_in, const int* in_sizes, int n_in,
                              void* d_out, int out_size, void* d_ws, size_t ws_size,
                              hipStream_t stream) {
  (void)in_sizes; (void)n_in; (void)out_size;
  const float* x = (const float*)d_in[0];
  const int* te = (const int*)d_in[1];
  const int* reo_all = (const int*)d_in[2];
  const int* ori_parts = (const int*)d_in[3];
  const int* reo_parts = (const int*)d_in[4];
  const float* w_st = (const float*)d_in[5];
  const float* b_st = (const float*)d_in[6];
  const float* node_emb = (const float*)d_in[7];
  const float* tod_emb = (const float*)d_in[8];
  const float* dow_emb = (const float*)d_in[9];
  const float* s_qkv_w = (const float*)d_in[10];
  const float* s_qkv_b = (const float*)d_in[11];
  const float* s_proj_w = (const float*)d_in[12];
  const float* s_proj_b = (const float*)d_in[13];
  const float* s_fc1_w = (const float*)d_in[14];
  const float* s_fc1_b = (const float*)d_in[15];
  const float* s_fc2_w = (const float*)d_in[16];
  const float* s_fc2_b = (const float*)d_in[17];
  const float* n_qkv_w = (const float*)d_in[18];
  const float* n_qkv_b = (const float*)d_in[19];
  const float* n_proj_w = (const float*)d_in[20];
  const float* n_proj_b = (const float*)d_in[21];
  const float* n_fc1_w = (const float*)d_in[22];
  const float* n_fc1_b = (const float*)d_in[23];
  const float* n_fc2_w = (const float*)d_in[24];
  const float* n_fc2_b = (const float*)d_in[25];
  const float* w_reg = (const float*)d_in[26];
  const float* b_reg = (const float*)d_in[27];
  (void)reo_all;

  const size_t REX_BYTES = (size_t)NB * TPN * NODES * D * 4;  // 134217728
  if (ws_size < REX_BYTES + 1179648) return;
  float* rex = (float*)d_ws;
  u16* wt = (u16*)((char*)d_ws + REX_BYTES);
  u16* s_qkv_t = wt + 0;
  u16* s_prj_t = wt + 147456;
  u16* s_fc1_t = wt + 196608;
  u16* s_fc2_t = wt + 245760;
  u16* n_qkv_t = wt + 294912;
  u16* n_prj_t = wt + 442368;
  u16* n_fc1_t = wt + 491520;
  u16* n_fc2_t = wt + 540672;

  k_prep<<<(3 * 128 * 384 + 255) / 256, 256, 0, stream>>>(s_qkv_w, s_qkv_t, 128, 384);
  k_prep<<<(3 * 128 * 128 + 255) / 256, 256, 0, stream>>>(s_proj_w, s_prj_t, 128, 128);
  k_prep<<<(3 * 128 * 128 + 255) / 256, 256, 0, stream>>>(s_fc1_w, s_fc1_t, 128, 128);
  k_prep<<<(3 * 128 * 128 + 255) / 256, 256, 0, stream>>>(s_fc2_w, s_fc2_t, 128, 128);
  k_prep<<<(3 * 128 * 384 + 255) / 256, 256, 0, stream>>>(n_qkv_w, n_qkv_t, 128, 384);
  k_prep<<<(3 * 128 * 128 + 255) / 256, 256, 0, stream>>>(n_proj_w, n_prj_t, 128, 128);
  k_prep<<<(3 * 128 * 128 + 255) / 256, 256, 0, stream>>>(n_fc1_w, n_fc1_t, 128, 128);
  k_prep<<<(3 * 128 * 128 + 255) / 256, 256, 0, stream>>>(n_fc2_w, n_fc2_t, 128, 128);

  k_embed<<<NB * TPN * (NODES / 16), 256, 0, stream>>>(
      x, te, reo_parts, w_st, b_st, node_emb, tod_emb, dow_emb, rex);

  for (int l = 0; l < 3; ++l) {
    k_spatial_mlp<<<NB * TPN * P, 128, 0, stream>>>(
        rex, s_qkv_t + (size_t)l * 49152, s_qkv_b + l * 384,
        s_prj_t + (size_t)l * 16384, s_proj_b + l * 128,
        s_fc1_t + (size_t)l * 16384, s_fc1_b + l * 128,
        s_fc2_t + (size_t)l * 16384, s_fc2_b + l * 128);
    k_cross_mlp<<<NB * TPN * NPS, 512, 0, stream>>>(
        rex, n_qkv_t + (size_t)l * 49152, n_qkv_b + l * 384,
        n_prj_t + (size_t)l * 16384, n_proj_b + l * 128,
        n_fc1_t + (size_t)l * 16384, n_fc1_b + l * 128,
        n_fc2_t + (size_t)l * 16384, n_fc2_b + l * 128);
  }

  k_readout<<<NB * (NODES / 64), 256, 0, stream>>>(
      rex, ori_parts, reo_parts, w_reg, b_reg, (float*)d_out);
}

// Round 4
// 3261.392 us; speedup vs baseline: 1.0391x; 1.0391x over previous
//
#include <hip/hip_runtime.h>

#define DEV __device__ __forceinline__
typedef __attribute__((ext_vector_type(8))) short s16x8;
typedef __attribute__((ext_vector_type(4))) float f32x4;
typedef unsigned short u16;

// ---------- constants ----------
#define NB 16      // B
#define TPN 2
#define NODES 8192
#define D 128
#define P 256
#define NPS 32
#define OUT_LEN 12

DEV f32x4 mfma16(s16x8 a, s16x8 b, f32x4 c) {
  return __builtin_amdgcn_mfma_f32_16x16x32_bf16(a, b, c, 0, 0, 0);
}

DEV short f2bf(float f) {
  union { float f; unsigned u; } v; v.f = f;
  unsigned r = v.u + 0x7fffu + ((v.u >> 16) & 1u);
  return (short)(r >> 16);
}

// swizzled LDS addressing: 256B-row and 512B-row buffers, XOR bits 4-6 by row&7
DEV int swz256(int row, int b) { return (row << 8) + (b ^ ((row & 7) << 4)); }
DEV int swz512(int row, int b) { return (row << 9) + (b ^ ((row & 7) << 4)); }

// A-fragment load: lane l -> row = mbase+(l&15), k = kbase+(l>>4)*8 .. +8
DEV s16x8 ldsA(const char* base, int mbase, int kbase, int lane) {
  int row = mbase + (lane & 15);
  int b = (kbase + ((lane >> 4) << 3)) << 1;
  return *(const s16x8*)(base + swz256(row, b));
}

// butterfly reduce across lane bits 0..3 (16-lane row groups)
DEV float rowred(float v) {
  v += __shfl_xor(v, 1);
  v += __shfl_xor(v, 2);
  v += __shfl_xor(v, 4);
  v += __shfl_xor(v, 8);
  return v;
}
DEV float rowmax(float v) {
  v = fmaxf(v, __shfl_xor(v, 1));
  v = fmaxf(v, __shfl_xor(v, 2));
  v = fmaxf(v, __shfl_xor(v, 4));
  v = fmaxf(v, __shfl_xor(v, 8));
  return v;
}

// ---------------- weight prep: f32 [3][K][N] -> bf16 [3][N][K] ----------------
__global__ void k_prep(const float* __restrict__ src, u16* __restrict__ dst, int K, int N) {
  int idx = blockIdx.x * 256 + threadIdx.x;
  int total = 3 * K * N;
  if (idx >= total) return;
  int l = idx / (K * N);
  int r = idx - l * K * N;
  int n = r / K;
  int k = r - n * K;
  dst[idx] = (u16)f2bf(src[l * K * N + k * N + n]);
}

// ---------------- embedding (scatter form: coalesced reads, 512B row writes) ----------------
__global__ __launch_bounds__(256) void k_embed(
    const float* __restrict__ x, const int* __restrict__ te, const int* __restrict__ reo_parts,
    const float* __restrict__ w_st, const float* __restrict__ b_st,
    const float* __restrict__ node_emb, const float* __restrict__ tod_emb,
    const float* __restrict__ dow_emb, float* __restrict__ rex) {
  __shared__ float sx[12][16], s0[12][16], s1[12][16];
  __shared__ int sed[2][16];
  __shared__ int sj[16];
  __shared__ float hb[16][132];
  int gid = blockIdx.x;
  int chunk = gid & 511, bt = gid >> 9;
  int b = bt >> 1, tt = bt & 1;
  int tid = threadIdx.x;
  int nl = tid & 15, c = tid >> 4;
  int n = chunk * 16 + nl;
  if (c < 12) {
    size_t off = ((size_t)(b * 24 + tt * 12 + c)) * NODES + n;
    sx[c][nl] = x[off];
    int2 t2 = *(const int2*)(te + 2 * off);
    s0[c][nl] = (float)t2.x * (1.0f / 288.0f);
    s1[c][nl] = (float)t2.y * (1.0f / 7.0f);
  } else if (c == 12) {
    size_t off = ((size_t)(b * 24 + 22 + tt)) * NODES + n;
    int2 t2 = *(const int2*)(te + 2 * off);
    sed[0][nl] = t2.x;
    sed[1][nl] = t2.y;
  } else if (c == 13) {
    sj[nl] = reo_parts[n];
  }
  __syncthreads();
  int db = c * 8;
  float o[8];
#pragma unroll
  for (int dd = 0; dd < 8; ++dd) {
    int d = db + dd;
    float v;
    if (d < 64) {
      float acc = b_st[d];
      const float* wd = w_st + d * 36;
#pragma unroll
      for (int p = 0; p < 12; ++p)
        acc += sx[p][nl] * wd[p] + s0[p][nl] * wd[12 + p] + s1[p][nl] * wd[24 + p];
      v = acc;
    } else if (d < 80) {
      v = tod_emb[sed[0][nl] * 16 + (d - 64)];
    } else if (d < 96) {
      v = dow_emb[sed[1][nl] * 16 + (d - 80)];
    } else {
      v = node_emb[n * 32 + (d - 96)];
    }
    o[dd] = v;
  }
  *(float4*)&hb[nl][db] = make_float4(o[0], o[1], o[2], o[3]);
  *(float4*)&hb[nl][db + 4] = make_float4(o[4], o[5], o[6], o[7]);
  __syncthreads();
  int row = tid >> 4, cw = tid & 15;
  float4 v0 = *(float4*)&hb[row][cw * 8];
  float4 v1 = *(float4*)&hb[row][cw * 8 + 4];
  float* dst = rex + ((size_t)bt * NODES + sj[row]) * D + cw * 8;
  *(float4*)dst = v0;
  *(float4*)(dst + 4) = v1;
}

// ---------------- fused spatial attention + MLP: 2 waves per 32-token patch ----------------
__global__ __launch_bounds__(128, 3) void k_spatial_mlp(
    float* __restrict__ rex,
    const u16* __restrict__ wqkv, const float* __restrict__ bqkv,
    const u16* __restrict__ wprj, const float* __restrict__ bprj,
    const u16* __restrict__ w1t, const float* __restrict__ b1,
    const u16* __restrict__ w2t, const float* __restrict__ b2) {
  __shared__ __align__(16) char sm[26624];
  char* Xb = sm;             // 32 x 256B swz
  char* Kb = sm + 8192;      // 32 x 256B swz
  char* VT = sm + 16384;     // 128 rows x 80B
  int tid = threadIdx.x;
  int w = tid >> 6, lane = tid & 63;
  int r = lane & 15, g = lane >> 4;
  float* X = rex + (size_t)blockIdx.x * (NPS * D);

  float xreg[8][4];
#pragma unroll
  for (int nt = 0; nt < 8; ++nt)
#pragma unroll
    for (int e = 0; e < 4; ++e)
      xreg[nt][e] = X[(w * 16 + g * 4 + e) * D + nt * 16 + r];

  float mn[4], rs[4];
#pragma unroll
  for (int e = 0; e < 4; ++e) {
    float s = 0.f, s2 = 0.f;
#pragma unroll
    for (int nt = 0; nt < 8; ++nt) { float v = xreg[nt][e]; s += v; s2 += v * v; }
    s = rowred(s); s2 = rowred(s2);
    float m = s * 0.0078125f;
    mn[e] = m;
    rs[e] = rsqrtf(s2 * 0.0078125f - m * m + 1e-6f);
  }
#pragma unroll
  for (int nt = 0; nt < 8; ++nt)
#pragma unroll
    for (int e = 0; e < 4; ++e)
      *(u16*)(Xb + swz256(w * 16 + g * 4 + e, (nt * 16 + r) * 2)) =
          (u16)f2bf((xreg[nt][e] - mn[e]) * rs[e]);
  s16x8 ax[4];
#pragma unroll
  for (int kt = 0; kt < 4; ++kt) ax[kt] = ldsA(Xb, w * 16, kt * 32, lane);

  for (int nt = 0; nt < 24; ++nt) {
    int n = nt * 16 + r;
    f32x4 a0 = {0.f, 0.f, 0.f, 0.f};
#pragma unroll
    for (int kt = 0; kt < 4; ++kt) {
      s16x8 b = *(const s16x8*)(wqkv + (size_t)n * D + kt * 32 + g * 8);
      a0 = mfma16(ax[kt], b, a0);
    }
    float bias = bqkv[n];
#pragma unroll
    for (int e = 0; e < 4; ++e) {
      float v0 = a0[e] + bias;
      int t0 = w * 16 + g * 4 + e;
      if (nt < 8) {
        *(u16*)(Xb + swz256(t0, n * 2)) = (u16)f2bf(v0);
      } else if (nt < 16) {
        *(u16*)(Kb + swz256(t0, (n - 128) * 2)) = (u16)f2bf(v0);
      } else {
        *(u16*)(VT + (n - 256) * 80 + t0 * 2) = (u16)f2bf(v0);
      }
    }
  }
  __syncthreads();

  s16x8 aqf[4];
#pragma unroll
  for (int kt = 0; kt < 4; ++kt) aqf[kt] = ldsA(Xb, w * 16, kt * 32, lane);
  const float scale = 0.08838834764831845f;
  f32x4 sc[2];
#pragma unroll
  for (int nt2 = 0; nt2 < 2; ++nt2) {
    f32x4 acc = {0.f, 0.f, 0.f, 0.f};
#pragma unroll
    for (int kt = 0; kt < 4; ++kt) {
      s16x8 b = ldsA(Kb, nt2 * 16, kt * 32, lane);
      acc = mfma16(aqf[kt], b, acc);
    }
    sc[nt2] = acc * scale;
  }
  __syncthreads();

#pragma unroll
  for (int e = 0; e < 4; ++e) {
    float v0 = sc[0][e], v1 = sc[1][e];
    float m = fmaxf(v0, v1);
    m = rowmax(m);
    float p0 = __expf(v0 - m), p1 = __expf(v1 - m);
    float s = rowred(p0 + p1);
    float ri = 1.0f / s;
    int row = w * 16 + g * 4 + e;
    *(u16*)(Kb + swz256(row, r * 2)) = (u16)f2bf(p0 * ri);
    *(u16*)(Kb + swz256(row, (16 + r) * 2)) = (u16)f2bf(p1 * ri);
  }

  {
    s16x8 af = ldsA(Kb, w * 16, 0, lane);
#pragma unroll
    for (int nt = 0; nt < 8; ++nt) {
      s16x8 bv = *(const s16x8*)(VT + (nt * 16 + r) * 80 + g * 16);
      f32x4 acc = {0.f, 0.f, 0.f, 0.f};
      acc = mfma16(af, bv, acc);
#pragma unroll
      for (int e = 0; e < 4; ++e)
        *(u16*)(Xb + swz256(w * 16 + g * 4 + e, (nt * 16 + r) * 2)) = (u16)f2bf(acc[e]);
    }
  }

  s16x8 aav[4];
#pragma unroll
  for (int kt = 0; kt < 4; ++kt) aav[kt] = ldsA(Xb, w * 16, kt * 32, lane);
#pragma unroll
  for (int nt = 0; nt < 8; ++nt) {
    int n = nt * 16 + r;
    f32x4 a0 = {0.f, 0.f, 0.f, 0.f};
#pragma unroll
    for (int kt = 0; kt < 4; ++kt) {
      s16x8 b = *(const s16x8*)(wprj + (size_t)n * D + kt * 32 + g * 8);
      a0 = mfma16(aav[kt], b, a0);
    }
    float bias = bprj[n];
#pragma unroll
    for (int e = 0; e < 4; ++e) xreg[nt][e] += a0[e] + bias;
  }

#pragma unroll
  for (int e = 0; e < 4; ++e) {
    float s = 0.f, s2 = 0.f;
#pragma unroll
    for (int nt = 0; nt < 8; ++nt) { float v = xreg[nt][e]; s += v; s2 += v * v; }
    s = rowred(s); s2 = rowred(s2);
    float m = s * 0.0078125f;
    mn[e] = m;
    rs[e] = rsqrtf(s2 * 0.0078125f - m * m + 1e-6f);
  }
#pragma unroll
  for (int nt = 0; nt < 8; ++nt)
#pragma unroll
    for (int e = 0; e < 4; ++e)
      *(u16*)(Kb + swz256(w * 16 + g * 4 + e, (nt * 16 + r) * 2)) =
          (u16)f2bf((xreg[nt][e] - mn[e]) * rs[e]);
  s16x8 ah[4];
#pragma unroll
  for (int kt = 0; kt < 4; ++kt) ah[kt] = ldsA(Kb, w * 16, kt * 32, lane);

#pragma unroll
  for (int nt = 0; nt < 8; ++nt) {
    int n = nt * 16 + r;
    f32x4 a0 = {0.f, 0.f, 0.f, 0.f};
#pragma unroll
    for (int kt = 0; kt < 4; ++kt) {
      s16x8 b = *(const s16x8*)(w1t + (size_t)n * D + kt * 32 + g * 8);
      a0 = mfma16(ah[kt], b, a0);
    }
    float bias = b1[n];
#pragma unroll
    for (int e = 0; e < 4; ++e) {
      float v0 = a0[e] + bias;
      v0 = 0.5f * v0 * (1.0f + erff(v0 * 0.70710678118654752f));
      *(u16*)(Xb + swz256(w * 16 + g * 4 + e, n * 2)) = (u16)f2bf(v0);
    }
  }
  s16x8 ah2[4];
#pragma unroll
  for (int kt = 0; kt < 4; ++kt) ah2[kt] = ldsA(Xb, w * 16, kt * 32, lane);

#pragma unroll
  for (int nt = 0; nt < 8; ++nt) {
    int n = nt * 16 + r;
    f32x4 a0 = {0.f, 0.f, 0.f, 0.f};
#pragma unroll
    for (int kt = 0; kt < 4; ++kt) {
      s16x8 b = *(const s16x8*)(w2t + (size_t)n * D + kt * 32 + g * 8);
      a0 = mfma16(ah2[kt], b, a0);
    }
    float bias = b2[n];
#pragma unroll
    for (int e = 0; e < 4; ++e) xreg[nt][e] += a0[e] + bias;
  }
#pragma unroll
  for (int nt = 0; nt < 8; ++nt)
#pragma unroll
    for (int e = 0; e < 4; ++e)
      X[(w * 16 + g * 4 + e) * D + nt * 16 + r] = xreg[nt][e];
}

// ---------------- fused cross attention + MLP: 16 waves / seq, 16 tokens / wave ----------------
// LDS: Kb 64KB | VT 64KB | Pscr 20KB. Wave scratch aliases: pre-KV -> VT, post-attn -> Kb.
__global__ __launch_bounds__(1024, 4) void k_cross_mlp(
    float* __restrict__ rex,
    const u16* __restrict__ wqkv, const float* __restrict__ bqkv,
    const u16* __restrict__ wprj, const float* __restrict__ bprj,
    const u16* __restrict__ w1t, const float* __restrict__ b1,
    const u16* __restrict__ w2t, const float* __restrict__ b2) {
  __shared__ __align__(16) char sm[151552];
  char* Kb = sm;            // 256 x 256B swz (K rows)
  char* VT = sm + 65536;    // 128 x 512B swz (V^T)
  int tid = threadIdx.x;
  int w = tid >> 6, lane = tid & 63;
  int r = lane & 15, g = lane >> 4;
  char* scrQ = sm + 65536 + w * 4096;   // pre-KV wave scratch (VT alias)
  char* scrO = sm + w * 4096;           // post-attn wave scratch (Kb alias)
  char* Pscr = sm + 131072 + w * 1280;  // 16 rows x 80B (P tiles)

  int sq = blockIdx.x;
  int bt = sq >> 5, i = sq & 31;
  float* X0 = rex + (size_t)bt * (NODES * D) + i * D;
  const int TS = NPS * D;  // 4096 floats between cross-sequence tokens

  // ---- load own 16 tokens in C-layout: xreg[nt][e] = X[w*16+g*4+e][nt*16+r]
  float xreg[8][4];
#pragma unroll
  for (int nt = 0; nt < 8; ++nt)
#pragma unroll
    for (int e = 0; e < 4; ++e)
      xreg[nt][e] = X0[(size_t)(w * 16 + g * 4 + e) * TS + nt * 16 + r];

  // ---- LN1 in-register -> scrQ -> ax
  s16x8 ax[4];
  {
    float mn[4], rs[4];
#pragma unroll
    for (int e = 0; e < 4; ++e) {
      float s = 0.f, s2 = 0.f;
#pragma unroll
      for (int nt = 0; nt < 8; ++nt) { float v = xreg[nt][e]; s += v; s2 += v * v; }
      s = rowred(s); s2 = rowred(s2);
      float m = s * 0.0078125f;
      mn[e] = m;
      rs[e] = rsqrtf(s2 * 0.0078125f - m * m + 1e-6f);
    }
#pragma unroll
    for (int nt = 0; nt < 8; ++nt)
#pragma unroll
      for (int e = 0; e < 4; ++e)
        *(u16*)(scrQ + swz256(g * 4 + e, (nt * 16 + r) * 2)) =
            (u16)f2bf((xreg[nt][e] - mn[e]) * rs[e]);
#pragma unroll
    for (int kt = 0; kt < 4; ++kt) ax[kt] = ldsA(scrQ, 0, kt * 32, lane);
  }

  // ---- Q GEMM (own 16 tokens) -> scrQ -> aq
  s16x8 aq[4];
  for (int nt = 0; nt < 8; ++nt) {
    int n = nt * 16 + r;
    f32x4 acc = {0.f, 0.f, 0.f, 0.f};
#pragma unroll
    for (int kt = 0; kt < 4; ++kt) {
      s16x8 b = *(const s16x8*)(wqkv + (size_t)n * D + kt * 32 + g * 8);
      acc = mfma16(ax[kt], b, acc);
    }
    float bias = bqkv[n];
#pragma unroll
    for (int e = 0; e < 4; ++e)
      *(u16*)(scrQ + swz256(g * 4 + e, n * 2)) = (u16)f2bf(acc[e] + bias);
  }
#pragma unroll
  for (int kt = 0; kt < 4; ++kt) aq[kt] = ldsA(scrQ, 0, kt * 32, lane);
  __syncthreads();  // everyone done with scrQ (VT alias) before V writes

  // ---- K,V GEMM (own 16 tokens) -> Kb / VT
  for (int nt = 0; nt < 16; ++nt) {
    int n = 128 + nt * 16 + r;
    f32x4 acc = {0.f, 0.f, 0.f, 0.f};
#pragma unroll
    for (int kt = 0; kt < 4; ++kt) {
      s16x8 b = *(const s16x8*)(wqkv + (size_t)n * D + kt * 32 + g * 8);
      acc = mfma16(ax[kt], b, acc);
    }
    float bias = bqkv[n];
#pragma unroll
    for (int e = 0; e < 4; ++e) {
      int tok = w * 16 + g * 4 + e;
      float v = acc[e] + bias;
      if (nt < 8)
        *(u16*)(Kb + swz256(tok, (nt * 16 + r) * 2)) = (u16)f2bf(v);
      else
        *(u16*)(VT + swz512((nt - 8) * 16 + r, tok * 2)) = (u16)f2bf(v);
    }
  }
  __syncthreads();  // K/V complete

  const float scale = 0.08838834764831845f;

  // ---- pass 1: raw-score row max (lane covers k = kt2*16 + r)
  float mx[4] = {-3.0e38f, -3.0e38f, -3.0e38f, -3.0e38f};
#pragma unroll 2
  for (int kt2 = 0; kt2 < 16; ++kt2) {
    f32x4 acc = {0.f, 0.f, 0.f, 0.f};
#pragma unroll
    for (int kt = 0; kt < 4; ++kt) {
      s16x8 b = ldsA(Kb, kt2 * 16, kt * 32, lane);
      acc = mfma16(aq[kt], b, acc);
    }
#pragma unroll
    for (int e = 0; e < 4; ++e) mx[e] = fmaxf(mx[e], acc[e]);
  }
#pragma unroll
  for (int e = 0; e < 4; ++e) mx[e] = rowmax(mx[e]);

  // ---- pass 2: recompute scores, exp, stage P tile, AV accumulate
  float sum[4] = {0.f, 0.f, 0.f, 0.f};
  f32x4 av[8];
#pragma unroll
  for (int nt = 0; nt < 8; ++nt) av[nt] = (f32x4){0.f, 0.f, 0.f, 0.f};
  for (int cc = 0; cc < 8; ++cc) {
#pragma unroll
    for (int sub = 0; sub < 2; ++sub) {
      int kt2 = cc * 2 + sub;
      f32x4 acc = {0.f, 0.f, 0.f, 0.f};
#pragma unroll
      for (int kt = 0; kt < 4; ++kt) {
        s16x8 b = ldsA(Kb, kt2 * 16, kt * 32, lane);
        acc = mfma16(aq[kt], b, acc);
      }
#pragma unroll
      for (int e = 0; e < 4; ++e) {
        float p = __expf((acc[e] - mx[e]) * scale);
        sum[e] += p;
        // row = q (g*4+e), col = local k (sub*16+r), 80B pitch
        *(u16*)(Pscr + (g * 4 + e) * 80 + (sub * 16 + r) * 2) = (u16)f2bf(p);
      }
    }
    // A-frag: lane -> row r, k = g*8..+8 within the 32-k chunk
    s16x8 ap = *(const s16x8*)(Pscr + r * 80 + g * 16);
#pragma unroll
    for (int nt = 0; nt < 8; ++nt) {
      s16x8 bv = *(const s16x8*)(VT + swz512(nt * 16 + r, (cc * 32 + g * 8) * 2));
      av[nt] = mfma16(ap, bv, av[nt]);
    }
  }
#pragma unroll
  for (int e = 0; e < 4; ++e) sum[e] = rowred(sum[e]);
  __syncthreads();  // all waves done with Kb/VT -> scrO (Kb alias) usable

  // ---- normalize AV -> scrO -> aav; proj + residual
  {
    float rinv[4];
#pragma unroll
    for (int e = 0; e < 4; ++e) rinv[e] = 1.0f / sum[e];
#pragma unroll
    for (int nt = 0; nt < 8; ++nt)
#pragma unroll
      for (int e = 0; e < 4; ++e)
        *(u16*)(scrO + swz256(g * 4 + e, (nt * 16 + r) * 2)) = (u16)f2bf(av[nt][e] * rinv[e]);
  }
  {
    s16x8 aav[4];
#pragma unroll
    for (int kt = 0; kt < 4; ++kt) aav[kt] = ldsA(scrO, 0, kt * 32, lane);
    for (int nt = 0; nt < 8; ++nt) {
      int n = nt * 16 + r;
      f32x4 acc = {0.f, 0.f, 0.f, 0.f};
#pragma unroll
      for (int kt = 0; kt < 4; ++kt) {
        s16x8 b = *(const s16x8*)(wprj + (size_t)n * D + kt * 32 + g * 8);
        acc = mfma16(aav[kt], b, acc);
      }
      float bias = bprj[n];
#pragma unroll
      for (int e = 0; e < 4; ++e) xreg[nt][e] += acc[e] + bias;
    }
  }

  // ---- fused MLP
  {
    float mn2[4], rs2[4];
#pragma unroll
    for (int e = 0; e < 4; ++e) {
      float s = 0.f, s2 = 0.f;
#pragma unroll
      for (int nt = 0; nt < 8; ++nt) { float v = xreg[nt][e]; s += v; s2 += v * v; }
      s = rowred(s); s2 = rowred(s2);
      float m = s * 0.0078125f;
      mn2[e] = m;
      rs2[e] = rsqrtf(s2 * 0.0078125f - m * m + 1e-6f);
    }
#pragma unroll
    for (int nt = 0; nt < 8; ++nt)
#pragma unroll
      for (int e = 0; e < 4; ++e)
        *(u16*)(scrO + swz256(g * 4 + e, (nt * 16 + r) * 2)) =
            (u16)f2bf((xreg[nt][e] - mn2[e]) * rs2[e]);
    s16x8 ah[4];
#pragma unroll
    for (int kt = 0; kt < 4; ++kt) ah[kt] = ldsA(scrO, 0, kt * 32, lane);
#pragma unroll
    for (int nt = 0; nt < 8; ++nt) {
      int n = nt * 16 + r;
      f32x4 acc = {0.f, 0.f, 0.f, 0.f};
#pragma unroll
      for (int kt = 0; kt < 4; ++kt) {
        s16x8 b = *(const s16x8*)(w1t + (size_t)n * D + kt * 32 + g * 8);
        acc = mfma16(ah[kt], b, acc);
      }
      float bias = b1[n];
#pragma unroll
      for (int e = 0; e < 4; ++e) {
        float v0 = acc[e] + bias;
        v0 = 0.5f * v0 * (1.0f + erff(v0 * 0.70710678118654752f));
        *(u16*)(scrO + swz256(g * 4 + e, n * 2)) = (u16)f2bf(v0);
      }
    }
    s16x8 ah2[4];
#pragma unroll
    for (int kt = 0; kt < 4; ++kt) ah2[kt] = ldsA(scrO, 0, kt * 32, lane);
#pragma unroll
    for (int nt = 0; nt < 8; ++nt) {
      int n = nt * 16 + r;
      f32x4 acc = {0.f, 0.f, 0.f, 0.f};
#pragma unroll
      for (int kt = 0; kt < 4; ++kt) {
        s16x8 b = *(const s16x8*)(w2t + (size_t)n * D + kt * 32 + g * 8);
        acc = mfma16(ah2[kt], b, acc);
      }
      float bias = b2[n];
#pragma unroll
      for (int e = 0; e < 4; ++e) xreg[nt][e] += acc[e] + bias;
    }
  }

  // ---- store
#pragma unroll
  for (int nt = 0; nt < 8; ++nt)
#pragma unroll
    for (int e = 0; e < 4; ++e)
      X0[(size_t)(w * 16 + g * 4 + e) * TS + nt * 16 + r] = xreg[nt][e];
}

// ---------------- readout ----------------
__global__ __launch_bounds__(256) void k_readout(
    const float* __restrict__ rex, const int* __restrict__ ori_idx,
    const int* __restrict__ reo_idx, const float* __restrict__ w_reg,
    const float* __restrict__ b_reg, float* __restrict__ out) {
  __shared__ float wl[3072];
  for (int i2 = threadIdx.x; i2 < 3072; i2 += 256) wl[i2] = w_reg[i2];
  __syncthreads();
  int b = blockIdx.x >> 7;
  int chunk = blockIdx.x & 127;
  int m = chunk * 64 + (threadIdx.x >> 2);
  int q = threadIdx.x & 3;
  int nOut = ori_idx[m];
  int j = reo_idx[m];
  int t = q >> 1;
  const float* src = rex + ((size_t)(b * 2 + t) * NODES + j) * D + (q & 1) * 64;
  float acc[12] = {0.f, 0.f, 0.f, 0.f, 0.f, 0.f, 0.f, 0.f, 0.f, 0.f, 0.f, 0.f};
#pragma unroll
  for (int k = 0; k < 64; k += 4) {
    float4 v = *(const float4*)(src + k);
#pragma unroll
    for (int o = 0; o < 12; ++o) {
      float4 wv = *(const float4*)(&wl[o * 256 + q * 64 + k]);
      acc[o] += v.x * wv.x + v.y * wv.y + v.z * wv.z + v.w * wv.w;
    }
  }
#pragma unroll
  for (int o = 0; o < 12; ++o) {
    acc[o] += __shfl_xor(acc[o], 1);
    acc[o] += __shfl_xor(acc[o], 2);
  }
  if (q == 0) {
#pragma unroll
    for (int o = 0; o < 12; ++o)
      out[((size_t)b * 12 + o) * NODES + nOut] = acc[o] + b_reg[o];
  }
}

// ---------------- host ----------------
extern "C" void kernel_launch(void* const* d_in, const int* in_sizes, int n_in,
                              void* d_out, int out_size, void* d_ws, size_t ws_size,
                              hipStream_t stream) {
  (void)in_sizes; (void)n_in; (void)out_size;
  const float* x = (const float*)d_in[0];
  const int* te = (const int*)d_in[1];
  const int* reo_all = (const int*)d_in[2];
  const int* ori_parts = (const int*)d_in[3];
  const int* reo_parts = (const int*)d_in[4];
  const float* w_st = (const float*)d_in[5];
  const float* b_st = (const float*)d_in[6];
  const float* node_emb = (const float*)d_in[7];
  const float* tod_emb = (const float*)d_in[8];
  const float* dow_emb = (const float*)d_in[9];
  const float* s_qkv_w = (const float*)d_in[10];
  const float* s_qkv_b = (const float*)d_in[11];
  const float* s_proj_w = (const float*)d_in[12];
  const float* s_proj_b = (const float*)d_in[13];
  const float* s_fc1_w = (const float*)d_in[14];
  const float* s_fc1_b = (const float*)d_in[15];
  const float* s_fc2_w = (const float*)d_in[16];
  const float* s_fc2_b = (const float*)d_in[17];
  const float* n_qkv_w = (const float*)d_in[18];
  const float* n_qkv_b = (const float*)d_in[19];
  const float* n_proj_w = (const float*)d_in[20];
  const float* n_proj_b = (const float*)d_in[21];
  const float* n_fc1_w = (const float*)d_in[22];
  const float* n_fc1_b = (const float*)d_in[23];
  const float* n_fc2_w = (const float*)d_in[24];
  const float* n_fc2_b = (const float*)d_in[25];
  const float* w_reg = (const float*)d_in[26];
  const float* b_reg = (const float*)d_in[27];
  (void)reo_all;

  const size_t REX_BYTES = (size_t)NB * TPN * NODES * D * 4;  // 134217728
  if (ws_size < REX_BYTES + 1179648) return;
  float* rex = (float*)d_ws;
  u16* wt = (u16*)((char*)d_ws + REX_BYTES);
  u16* s_qkv_t = wt + 0;
  u16* s_prj_t = wt + 147456;
  u16* s_fc1_t = wt + 196608;
  u16* s_fc2_t = wt + 245760;
  u16* n_qkv_t = wt + 294912;
  u16* n_prj_t = wt + 442368;
  u16* n_fc1_t = wt + 491520;
  u16* n_fc2_t = wt + 540672;

  k_prep<<<(3 * 128 * 384 + 255) / 256, 256, 0, stream>>>(s_qkv_w, s_qkv_t, 128, 384);
  k_prep<<<(3 * 128 * 128 + 255) / 256, 256, 0, stream>>>(s_proj_w, s_prj_t, 128, 128);
  k_prep<<<(3 * 128 * 128 + 255) / 256, 256, 0, stream>>>(s_fc1_w, s_fc1_t, 128, 128);
  k_prep<<<(3 * 128 * 128 + 255) / 256, 256, 0, stream>>>(s_fc2_w, s_fc2_t, 128, 128);
  k_prep<<<(3 * 128 * 384 + 255) / 256, 256, 0, stream>>>(n_qkv_w, n_qkv_t, 128, 384);
  k_prep<<<(3 * 128 * 128 + 255) / 256, 256, 0, stream>>>(n_proj_w, n_prj_t, 128, 128);
  k_prep<<<(3 * 128 * 128 + 255) / 256, 256, 0, stream>>>(n_fc1_w, n_fc1_t, 128, 128);
  k_prep<<<(3 * 128 * 128 + 255) / 256, 256, 0, stream>>>(n_fc2_w, n_fc2_t, 128, 128);

  k_embed<<<NB * TPN * (NODES / 16), 256, 0, stream>>>(
      x, te, reo_parts, w_st, b_st, node_emb, tod_emb, dow_emb, rex);

  for (int l = 0; l < 3; ++l) {
    k_spatial_mlp<<<NB * TPN * P, 128, 0, stream>>>(
        rex, s_qkv_t + (size_t)l * 49152, s_qkv_b + l * 384,
        s_prj_t + (size_t)l * 16384, s_proj_b + l * 128,
        s_fc1_t + (size_t)l * 16384, s_fc1_b + l * 128,
        s_fc2_t + (size_t)l * 16384, s_fc2_b + l * 128);
    k_cross_mlp<<<NB * TPN * NPS, 1024, 0, stream>>>(
        rex, n_qkv_t + (size_t)l * 49152, n_qkv_b + l * 384,
        n_prj_t + (size_t)l * 16384, n_proj_b + l * 128,
        n_fc1_t + (size_t)l * 16384, n_fc1_b + l * 128,
        n_fc2_t + (size_t)l * 16384, n_fc2_b + l * 128);
  }

  k_readout<<<NB * (NODES / 64), 256, 0, stream>>>(
      rex, ori_parts, reo_parts, w_reg, b_reg, (float*)d_out);
}

// Round 5
// 2425.502 us; speedup vs baseline: 1.3971x; 1.3446x over previous
//
#include <hip/hip_runtime.h>

#define DEV __device__ __forceinline__
typedef __attribute__((ext_vector_type(8))) short s16x8;
typedef __attribute__((ext_vector_type(4))) float f32x4;
typedef unsigned short u16;

// ---------- constants ----------
#define NB 16      // B
#define TPN 2
#define NODES 8192
#define D 128
#define P 256
#define NPS 32
#define OUT_LEN 12

DEV f32x4 mfma16(s16x8 a, s16x8 b, f32x4 c) {
  return __builtin_amdgcn_mfma_f32_16x16x32_bf16(a, b, c, 0, 0, 0);
}

DEV short f2bf(float f) {
  union { float f; unsigned u; } v; v.f = f;
  unsigned r = v.u + 0x7fffu + ((v.u >> 16) & 1u);
  return (short)(r >> 16);
}

// swizzled LDS addressing: 256B-row and 512B-row buffers, XOR bits 4-6 by row&7
DEV int swz256(int row, int b) { return (row << 8) + (b ^ ((row & 7) << 4)); }
DEV int swz512(int row, int b) { return (row << 9) + (b ^ ((row & 7) << 4)); }

// A-fragment load: lane l -> row = mbase+(l&15), k = kbase+(l>>4)*8 .. +8
DEV s16x8 ldsA(const char* base, int mbase, int kbase, int lane) {
  int row = mbase + (lane & 15);
  int b = (kbase + ((lane >> 4) << 3)) << 1;
  return *(const s16x8*)(base + swz256(row, b));
}

// butterfly reduce across lane bits 0..3 (16-lane row groups)
DEV float rowred(float v) {
  v += __shfl_xor(v, 1);
  v += __shfl_xor(v, 2);
  v += __shfl_xor(v, 4);
  v += __shfl_xor(v, 8);
  return v;
}
DEV float rowmax(float v) {
  v = fmaxf(v, __shfl_xor(v, 1));
  v = fmaxf(v, __shfl_xor(v, 2));
  v = fmaxf(v, __shfl_xor(v, 4));
  v = fmaxf(v, __shfl_xor(v, 8));
  return v;
}
// reduce across g-groups (lane bits 4,5): full 128-col row sum for A-layout
DEV float gred(float v) {
  v += __shfl_xor(v, 16);
  v += __shfl_xor(v, 32);
  return v;
}

// stage one 64-col x 128-k bf16 weight tile (16KB) into LDS, swz256 layout.
DEV void stageW(char* buf, const u16* __restrict__ w, int tid) {
  int col = tid >> 4, kc = tid & 15;
  s16x8 v = *(const s16x8*)(w + col * 128 + kc * 8);
  *(s16x8*)(buf + swz256(col, kc * 16)) = v;
}

// ---------------- weight prep: f32 [3][K][N] -> bf16 [3][N][K] ----------------
__global__ void k_prep(const float* __restrict__ src, u16* __restrict__ dst, int K, int N) {
  int idx = blockIdx.x * 256 + threadIdx.x;
  int total = 3 * K * N;
  if (idx >= total) return;
  int l = idx / (K * N);
  int r = idx - l * K * N;
  int n = r / K;
  int k = r - n * K;
  dst[idx] = (u16)f2bf(src[l * K * N + k * N + n]);
}

// ---------------- embedding (scatter form) ----------------
__global__ __launch_bounds__(256) void k_embed(
    const float* __restrict__ x, const int* __restrict__ te, const int* __restrict__ reo_parts,
    const float* __restrict__ w_st, const float* __restrict__ b_st,
    const float* __restrict__ node_emb, const float* __restrict__ tod_emb,
    const float* __restrict__ dow_emb, float* __restrict__ rex) {
  __shared__ float sx[12][16], s0[12][16], s1[12][16];
  __shared__ int sed[2][16];
  __shared__ int sj[16];
  __shared__ float hb[16][132];
  int gid = blockIdx.x;
  int chunk = gid & 511, bt = gid >> 9;
  int b = bt >> 1, tt = bt & 1;
  int tid = threadIdx.x;
  int nl = tid & 15, c = tid >> 4;
  int n = chunk * 16 + nl;
  if (c < 12) {
    size_t off = ((size_t)(b * 24 + tt * 12 + c)) * NODES + n;
    sx[c][nl] = x[off];
    int2 t2 = *(const int2*)(te + 2 * off);
    s0[c][nl] = (float)t2.x * (1.0f / 288.0f);
    s1[c][nl] = (float)t2.y * (1.0f / 7.0f);
  } else if (c == 12) {
    size_t off = ((size_t)(b * 24 + 22 + tt)) * NODES + n;
    int2 t2 = *(const int2*)(te + 2 * off);
    sed[0][nl] = t2.x;
    sed[1][nl] = t2.y;
  } else if (c == 13) {
    sj[nl] = reo_parts[n];
  }
  __syncthreads();
  int db = c * 8;
  float o[8];
#pragma unroll
  for (int dd = 0; dd < 8; ++dd) {
    int d = db + dd;
    float v;
    if (d < 64) {
      float acc = b_st[d];
      const float* wd = w_st + d * 36;
#pragma unroll
      for (int p = 0; p < 12; ++p)
        acc += sx[p][nl] * wd[p] + s0[p][nl] * wd[12 + p] + s1[p][nl] * wd[24 + p];
      v = acc;
    } else if (d < 80) {
      v = tod_emb[sed[0][nl] * 16 + (d - 64)];
    } else if (d < 96) {
      v = dow_emb[sed[1][nl] * 16 + (d - 80)];
    } else {
      v = node_emb[n * 32 + (d - 96)];
    }
    o[dd] = v;
  }
  *(float4*)&hb[nl][db] = make_float4(o[0], o[1], o[2], o[3]);
  *(float4*)&hb[nl][db + 4] = make_float4(o[4], o[5], o[6], o[7]);
  __syncthreads();
  int row = tid >> 4, cw = tid & 15;
  float4 v0 = *(float4*)&hb[row][cw * 8];
  float4 v1 = *(float4*)&hb[row][cw * 8 + 4];
  float* dst = rex + ((size_t)bt * NODES + sj[row]) * D + cw * 8;
  *(float4*)dst = v0;
  *(float4*)(dst + 4) = v1;
}

// ---------------- fused spatial attention + MLP: 2 waves per 32-token patch ----------------
__global__ __launch_bounds__(128, 3) void k_spatial_mlp(
    float* __restrict__ rex,
    const u16* __restrict__ wqkv, const float* __restrict__ bqkv,
    const u16* __restrict__ wprj, const float* __restrict__ bprj,
    const u16* __restrict__ w1t, const float* __restrict__ b1,
    const u16* __restrict__ w2t, const float* __restrict__ b2) {
  __shared__ __align__(16) char sm[26624];
  char* Xb = sm;             // 32 x 256B swz
  char* Kb = sm + 8192;      // 32 x 256B swz
  char* VT = sm + 16384;     // 128 rows x 80B
  int tid = threadIdx.x;
  int w = tid >> 6, lane = tid & 63;
  int r = lane & 15, g = lane >> 4;
  float* X = rex + (size_t)blockIdx.x * (NPS * D);

  float xreg[8][4];
#pragma unroll
  for (int nt = 0; nt < 8; ++nt)
#pragma unroll
    for (int e = 0; e < 4; ++e)
      xreg[nt][e] = X[(w * 16 + g * 4 + e) * D + nt * 16 + r];

  float mn[4], rs[4];
#pragma unroll
  for (int e = 0; e < 4; ++e) {
    float s = 0.f, s2 = 0.f;
#pragma unroll
    for (int nt = 0; nt < 8; ++nt) { float v = xreg[nt][e]; s += v; s2 += v * v; }
    s = rowred(s); s2 = rowred(s2);
    float m = s * 0.0078125f;
    mn[e] = m;
    rs[e] = rsqrtf(s2 * 0.0078125f - m * m + 1e-6f);
  }
#pragma unroll
  for (int nt = 0; nt < 8; ++nt)
#pragma unroll
    for (int e = 0; e < 4; ++e)
      *(u16*)(Xb + swz256(w * 16 + g * 4 + e, (nt * 16 + r) * 2)) =
          (u16)f2bf((xreg[nt][e] - mn[e]) * rs[e]);
  s16x8 ax[4];
#pragma unroll
  for (int kt = 0; kt < 4; ++kt) ax[kt] = ldsA(Xb, w * 16, kt * 32, lane);

  for (int nt = 0; nt < 24; ++nt) {
    int n = nt * 16 + r;
    f32x4 a0 = {0.f, 0.f, 0.f, 0.f};
#pragma unroll
    for (int kt = 0; kt < 4; ++kt) {
      s16x8 b = *(const s16x8*)(wqkv + (size_t)n * D + kt * 32 + g * 8);
      a0 = mfma16(ax[kt], b, a0);
    }
    float bias = bqkv[n];
#pragma unroll
    for (int e = 0; e < 4; ++e) {
      float v0 = a0[e] + bias;
      int t0 = w * 16 + g * 4 + e;
      if (nt < 8) {
        *(u16*)(Xb + swz256(t0, n * 2)) = (u16)f2bf(v0);
      } else if (nt < 16) {
        *(u16*)(Kb + swz256(t0, (n - 128) * 2)) = (u16)f2bf(v0);
      } else {
        *(u16*)(VT + (n - 256) * 80 + t0 * 2) = (u16)f2bf(v0);
      }
    }
  }
  __syncthreads();

  s16x8 aqf[4];
#pragma unroll
  for (int kt = 0; kt < 4; ++kt) aqf[kt] = ldsA(Xb, w * 16, kt * 32, lane);
  const float scale = 0.08838834764831845f;
  f32x4 sc[2];
#pragma unroll
  for (int nt2 = 0; nt2 < 2; ++nt2) {
    f32x4 acc = {0.f, 0.f, 0.f, 0.f};
#pragma unroll
    for (int kt = 0; kt < 4; ++kt) {
      s16x8 b = ldsA(Kb, nt2 * 16, kt * 32, lane);
      acc = mfma16(aqf[kt], b, acc);
    }
    sc[nt2] = acc * scale;
  }
  __syncthreads();

#pragma unroll
  for (int e = 0; e < 4; ++e) {
    float v0 = sc[0][e], v1 = sc[1][e];
    float m = fmaxf(v0, v1);
    m = rowmax(m);
    float p0 = __expf(v0 - m), p1 = __expf(v1 - m);
    float s = rowred(p0 + p1);
    float ri = 1.0f / s;
    int row = w * 16 + g * 4 + e;
    *(u16*)(Kb + swz256(row, r * 2)) = (u16)f2bf(p0 * ri);
    *(u16*)(Kb + swz256(row, (16 + r) * 2)) = (u16)f2bf(p1 * ri);
  }

  {
    s16x8 af = ldsA(Kb, w * 16, 0, lane);
#pragma unroll
    for (int nt = 0; nt < 8; ++nt) {
      s16x8 bv = *(const s16x8*)(VT + (nt * 16 + r) * 80 + g * 16);
      f32x4 acc = {0.f, 0.f, 0.f, 0.f};
      acc = mfma16(af, bv, acc);
#pragma unroll
      for (int e = 0; e < 4; ++e)
        *(u16*)(Xb + swz256(w * 16 + g * 4 + e, (nt * 16 + r) * 2)) = (u16)f2bf(acc[e]);
    }
  }

  s16x8 aav[4];
#pragma unroll
  for (int kt = 0; kt < 4; ++kt) aav[kt] = ldsA(Xb, w * 16, kt * 32, lane);
#pragma unroll
  for (int nt = 0; nt < 8; ++nt) {
    int n = nt * 16 + r;
    f32x4 a0 = {0.f, 0.f, 0.f, 0.f};
#pragma unroll
    for (int kt = 0; kt < 4; ++kt) {
      s16x8 b = *(const s16x8*)(wprj + (size_t)n * D + kt * 32 + g * 8);
      a0 = mfma16(aav[kt], b, a0);
    }
    float bias = bprj[n];
#pragma unroll
    for (int e = 0; e < 4; ++e) xreg[nt][e] += a0[e] + bias;
  }

#pragma unroll
  for (int e = 0; e < 4; ++e) {
    float s = 0.f, s2 = 0.f;
#pragma unroll
    for (int nt = 0; nt < 8; ++nt) { float v = xreg[nt][e]; s += v; s2 += v * v; }
    s = rowred(s); s2 = rowred(s2);
    float m = s * 0.0078125f;
    mn[e] = m;
    rs[e] = rsqrtf(s2 * 0.0078125f - m * m + 1e-6f);
  }
#pragma unroll
  for (int nt = 0; nt < 8; ++nt)
#pragma unroll
    for (int e = 0; e < 4; ++e)
      *(u16*)(Kb + swz256(w * 16 + g * 4 + e, (nt * 16 + r) * 2)) =
          (u16)f2bf((xreg[nt][e] - mn[e]) * rs[e]);
  s16x8 ah[4];
#pragma unroll
  for (int kt = 0; kt < 4; ++kt) ah[kt] = ldsA(Kb, w * 16, kt * 32, lane);

#pragma unroll
  for (int nt = 0; nt < 8; ++nt) {
    int n = nt * 16 + r;
    f32x4 a0 = {0.f, 0.f, 0.f, 0.f};
#pragma unroll
    for (int kt = 0; kt < 4; ++kt) {
      s16x8 b = *(const s16x8*)(w1t + (size_t)n * D + kt * 32 + g * 8);
      a0 = mfma16(ah[kt], b, a0);
    }
    float bias = b1[n];
#pragma unroll
    for (int e = 0; e < 4; ++e) {
      float v0 = a0[e] + bias;
      v0 = 0.5f * v0 * (1.0f + erff(v0 * 0.70710678118654752f));
      *(u16*)(Xb + swz256(w * 16 + g * 4 + e, n * 2)) = (u16)f2bf(v0);
    }
  }
  s16x8 ah2[4];
#pragma unroll
  for (int kt = 0; kt < 4; ++kt) ah2[kt] = ldsA(Xb, w * 16, kt * 32, lane);

#pragma unroll
  for (int nt = 0; nt < 8; ++nt) {
    int n = nt * 16 + r;
    f32x4 a0 = {0.f, 0.f, 0.f, 0.f};
#pragma unroll
    for (int kt = 0; kt < 4; ++kt) {
      s16x8 b = *(const s16x8*)(w2t + (size_t)n * D + kt * 32 + g * 8);
      a0 = mfma16(ah2[kt], b, a0);
    }
    float bias = b2[n];
#pragma unroll
    for (int e = 0; e < 4; ++e) xreg[nt][e] += a0[e] + bias;
  }
#pragma unroll
  for (int nt = 0; nt < 8; ++nt)
#pragma unroll
    for (int e = 0; e < 4; ++e)
      X[(w * 16 + g * 4 + e) * D + nt * 16 + r] = xreg[nt][e];
}

// ---------------- fused cross attention + MLP: 16 waves, LDS-staged weights ----------------
__global__ __launch_bounds__(1024, 4) void k_cross_mlp(
    float* __restrict__ rex,
    const u16* __restrict__ wqkv, const float* __restrict__ bqkv,
    const u16* __restrict__ wprj, const float* __restrict__ bprj,
    const u16* __restrict__ w1t, const float* __restrict__ b1,
    const u16* __restrict__ w2t, const float* __restrict__ b2) {
  __shared__ __align__(16) char sm[163840];
  char* Kb = sm;
  char* VT = sm + 65536;
  char* WSa = sm + 131072;
  char* WSb = sm + 147456;
  int tid = threadIdx.x;
  int w = tid >> 6, lane = tid & 63;
  int r = lane & 15, g = lane >> 4;
  char* scrQ = sm + 65536 + w * 4096;
  char* scrO = sm + w * 4096;
  char* Pscr = sm + 131072 + w * 1280;

  int sq = blockIdx.x;
  int bt = sq >> 5, i = sq & 31;
  float* X0 = rex + (size_t)bt * (NODES * D) + i * D;
  const int TS = NPS * D;
  float* Xrow = X0 + (size_t)(w * 16 + r) * TS;

  float xr[4][8];
#pragma unroll
  for (int kt = 0; kt < 4; ++kt) {
    float4 a = *(const float4*)(Xrow + kt * 32 + g * 8);
    float4 b = *(const float4*)(Xrow + kt * 32 + g * 8 + 4);
    xr[kt][0] = a.x; xr[kt][1] = a.y; xr[kt][2] = a.z; xr[kt][3] = a.w;
    xr[kt][4] = b.x; xr[kt][5] = b.y; xr[kt][6] = b.z; xr[kt][7] = b.w;
  }

  s16x8 ax[4];
  {
    float s = 0.f, s2 = 0.f;
#pragma unroll
    for (int kt = 0; kt < 4; ++kt)
#pragma unroll
      for (int j = 0; j < 8; ++j) { float v = xr[kt][j]; s += v; s2 += v * v; }
    s = gred(s); s2 = gred(s2);
    float m = s * 0.0078125f;
    float rsd = rsqrtf(s2 * 0.0078125f - m * m + 1e-6f);
#pragma unroll
    for (int kt = 0; kt < 4; ++kt) {
      s16x8 o;
#pragma unroll
      for (int j = 0; j < 8; ++j) o[j] = f2bf((xr[kt][j] - m) * rsd);
      ax[kt] = o;
    }
  }

  stageW(WSa, wqkv, tid);
  __syncthreads();
  s16x8 aq[4];
  for (int t = 0; t < 6; ++t) {
    const char* cur = (t & 1) ? WSb : WSa;
    if (t < 5) stageW((t & 1) ? WSa : WSb, wqkv + (size_t)(t + 1) * 8192, tid);
#pragma unroll
    for (int sub = 0; sub < 4; ++sub) {
      int colg = t * 64 + sub * 16 + r;
      f32x4 acc = {0.f, 0.f, 0.f, 0.f};
#pragma unroll
      for (int kt = 0; kt < 4; ++kt)
        acc = mfma16(ax[kt], ldsA(cur, sub * 16, kt * 32, lane), acc);
      float bias = bqkv[colg];
#pragma unroll
      for (int e = 0; e < 4; ++e) {
        float v = acc[e] + bias;
        int tok = w * 16 + g * 4 + e;
        if (t < 2) {
          *(u16*)(scrQ + swz256(g * 4 + e, colg * 2)) = (u16)f2bf(v);
        } else if (t < 4) {
          *(u16*)(Kb + swz256(tok, (colg - 128) * 2)) = (u16)f2bf(v);
        } else {
          *(u16*)(VT + swz512(colg - 256, tok * 2)) = (u16)f2bf(v);
        }
      }
    }
    if (t == 1) {
#pragma unroll
      for (int kt = 0; kt < 4; ++kt) aq[kt] = ldsA(scrQ, 0, kt * 32, lane);
    }
    __syncthreads();
  }

  const float scale = 0.08838834764831845f;

  float mx[4] = {-3.0e38f, -3.0e38f, -3.0e38f, -3.0e38f};
#pragma unroll 2
  for (int kt2 = 0; kt2 < 16; ++kt2) {
    f32x4 acc = {0.f, 0.f, 0.f, 0.f};
#pragma unroll
    for (int kt = 0; kt < 4; ++kt) {
      s16x8 b = ldsA(Kb, kt2 * 16, kt * 32, lane);
      acc = mfma16(aq[kt], b, acc);
    }
#pragma unroll
    for (int e = 0; e < 4; ++e) mx[e] = fmaxf(mx[e], acc[e]);
  }
#pragma unroll
  for (int e = 0; e < 4; ++e) mx[e] = rowmax(mx[e]);

  float sum[4] = {0.f, 0.f, 0.f, 0.f};
  f32x4 av[8];
#pragma unroll
  for (int nt = 0; nt < 8; ++nt) av[nt] = (f32x4){0.f, 0.f, 0.f, 0.f};
  for (int cc = 0; cc < 8; ++cc) {
#pragma unroll
    for (int sub = 0; sub < 2; ++sub) {
      int kt2 = cc * 2 + sub;
      f32x4 acc = {0.f, 0.f, 0.f, 0.f};
#pragma unroll
      for (int kt = 0; kt < 4; ++kt) {
        s16x8 b = ldsA(Kb, kt2 * 16, kt * 32, lane);
        acc = mfma16(aq[kt], b, acc);
      }
#pragma unroll
      for (int e = 0; e < 4; ++e) {
        float p = __expf((acc[e] - mx[e]) * scale);
        sum[e] += p;
        *(u16*)(Pscr + (g * 4 + e) * 80 + (sub * 16 + r) * 2) = (u16)f2bf(p);
      }
    }
    s16x8 ap = *(const s16x8*)(Pscr + r * 80 + g * 16);
#pragma unroll
    for (int nt = 0; nt < 8; ++nt) {
      s16x8 bv = *(const s16x8*)(VT + swz512(nt * 16 + r, (cc * 32 + g * 8) * 2));
      av[nt] = mfma16(ap, bv, av[nt]);
    }
  }
#pragma unroll
  for (int e = 0; e < 4; ++e) sum[e] = rowred(sum[e]);
  __syncthreads();

  {
    float rinv[4];
#pragma unroll
    for (int e = 0; e < 4; ++e) rinv[e] = 1.0f / sum[e];
#pragma unroll
    for (int nt = 0; nt < 8; ++nt)
#pragma unroll
      for (int e = 0; e < 4; ++e)
        *(u16*)(scrO + swz256(g * 4 + e, (nt * 16 + r) * 2)) = (u16)f2bf(av[nt][e] * rinv[e]);
  }
  s16x8 aav[4];
#pragma unroll
  for (int kt = 0; kt < 4; ++kt) aav[kt] = ldsA(scrO, 0, kt * 32, lane);

  stageW(WSa, wprj, tid);
  __syncthreads();
#pragma unroll
  for (int t = 0; t < 2; ++t) {
    const char* cur = t ? WSb : WSa;
    if (t == 0) stageW(WSb, wprj + 8192, tid);
#pragma unroll
    for (int sub = 0; sub < 4; ++sub) {
      int colg = t * 64 + sub * 16 + r;
      f32x4 acc = {0.f, 0.f, 0.f, 0.f};
#pragma unroll
      for (int kt = 0; kt < 4; ++kt)
        acc = mfma16(aav[kt], ldsA(cur, sub * 16, kt * 32, lane), acc);
      float bias = bprj[colg];
#pragma unroll
      for (int e = 0; e < 4; ++e) {
        int row = g * 4 + e;
        *(float*)(scrO + row * 256 + (((sub * 16 + r) * 4) ^ ((row & 7) << 4))) = acc[e] + bias;
      }
    }
#pragma unroll
    for (int kk = 0; kk < 2; ++kk) {
      int base = kk * 128 + g * 32;
      f32x4 u0 = *(const f32x4*)(scrO + r * 256 + (base ^ ((r & 7) << 4)));
      f32x4 u1 = *(const f32x4*)(scrO + r * 256 + ((base + 16) ^ ((r & 7) << 4)));
      int kt = t * 2 + kk;
      xr[kt][0] += u0[0]; xr[kt][1] += u0[1]; xr[kt][2] += u0[2]; xr[kt][3] += u0[3];
      xr[kt][4] += u1[0]; xr[kt][5] += u1[1]; xr[kt][6] += u1[2]; xr[kt][7] += u1[3];
    }
    __syncthreads();
  }

  s16x8 ah[4];
  {
    float s = 0.f, s2 = 0.f;
#pragma unroll
    for (int kt = 0; kt < 4; ++kt)
#pragma unroll
      for (int j = 0; j < 8; ++j) { float v = xr[kt][j]; s += v; s2 += v * v; }
    s = gred(s); s2 = gred(s2);
    float m = s * 0.0078125f;
    float rsd = rsqrtf(s2 * 0.0078125f - m * m + 1e-6f);
#pragma unroll
    for (int kt = 0; kt < 4; ++kt) {
      s16x8 o;
#pragma unroll
      for (int j = 0; j < 8; ++j) o[j] = f2bf((xr[kt][j] - m) * rsd);
      ah[kt] = o;
    }
  }

  stageW(WSa, w1t, tid);
  __syncthreads();
  s16x8 ah2[4];
#pragma unroll
  for (int t = 0; t < 2; ++t) {
    const char* cur = t ? WSb : WSa;
    if (t == 0) stageW(WSb, w1t + 8192, tid);
#pragma unroll
    for (int sub = 0; sub < 4; ++sub) {
      int colg = t * 64 + sub * 16 + r;
      f32x4 acc = {0.f, 0.f, 0.f, 0.f};
#pragma unroll
      for (int kt = 0; kt < 4; ++kt)
        acc = mfma16(ah[kt], ldsA(cur, sub * 16, kt * 32, lane), acc);
      float bias = b1[colg];
#pragma unroll
      for (int e = 0; e < 4; ++e) {
        float v0 = acc[e] + bias;
        v0 = 0.5f * v0 * (1.0f + erff(v0 * 0.70710678118654752f));
        *(u16*)(scrO + swz256(g * 4 + e, colg * 2)) = (u16)f2bf(v0);
      }
    }
    if (t == 1) {
#pragma unroll
      for (int kt = 0; kt < 4; ++kt) ah2[kt] = ldsA(scrO, 0, kt * 32, lane);
    }
    __syncthreads();
  }

  stageW(WSa, w2t, tid);
  __syncthreads();
#pragma unroll
  for (int t = 0; t < 2; ++t) {
    const char* cur = t ? WSb : WSa;
    if (t == 0) stageW(WSb, w2t + 8192, tid);
#pragma unroll
    for (int sub = 0; sub < 4; ++sub) {
      int colg = t * 64 + sub * 16 + r;
      f32x4 acc = {0.f, 0.f, 0.f, 0.f};
#pragma unroll
      for (int kt = 0; kt < 4; ++kt)
        acc = mfma16(ah2[kt], ldsA(cur, sub * 16, kt * 32, lane), acc);
      float bias = b2[colg];
#pragma unroll
      for (int e = 0; e < 4; ++e) {
        int row = g * 4 + e;
        *(float*)(scrO + row * 256 + (((sub * 16 + r) * 4) ^ ((row & 7) << 4))) = acc[e] + bias;
      }
    }
#pragma unroll
    for (int kk = 0; kk < 2; ++kk) {
      int base = kk * 128 + g * 32;
      f32x4 u0 = *(const f32x4*)(scrO + r * 256 + (base ^ ((r & 7) << 4)));
      f32x4 u1 = *(const f32x4*)(scrO + r * 256 + ((base + 16) ^ ((r & 7) << 4)));
      int kt = t * 2 + kk;
      xr[kt][0] += u0[0]; xr[kt][1] += u0[1]; xr[kt][2] += u0[2]; xr[kt][3] += u0[3];
      xr[kt][4] += u1[0]; xr[kt][5] += u1[1]; xr[kt][6] += u1[2]; xr[kt][7] += u1[3];
    }
    if (t == 0) __syncthreads();
  }

#pragma unroll
  for (int kt = 0; kt < 4; ++kt) {
    *(float4*)(Xrow + kt * 32 + g * 8) =
        make_float4(xr[kt][0], xr[kt][1], xr[kt][2], xr[kt][3]);
    *(float4*)(Xrow + kt * 32 + g * 8 + 4) =
        make_float4(xr[kt][4], xr[kt][5], xr[kt][6], xr[kt][7]);
  }
}

// ---------------- readout ----------------
__global__ __launch_bounds__(256) void k_readout(
    const float* __restrict__ rex, const int* __restrict__ ori_idx,
    const int* __restrict__ reo_idx, const float* __restrict__ w_reg,
    const float* __restrict__ b_reg, float* __restrict__ out) {
  __shared__ float wl[3072];
  for (int i2 = threadIdx.x; i2 < 3072; i2 += 256) wl[i2] = w_reg[i2];
  __syncthreads();
  int b = blockIdx.x >> 7;
  int chunk = blockIdx.x & 127;
  int m = chunk * 64 + (threadIdx.x >> 2);
  int q = threadIdx.x & 3;
  int nOut = ori_idx[m];
  int j = reo_idx[m];
  int t = q >> 1;
  const float* src = rex + ((size_t)(b * 2 + t) * NODES + j) * D + (q & 1) * 64;
  float acc[12] = {0.f, 0.f, 0.f, 0.f, 0.f, 0.f, 0.f, 0.f, 0.f, 0.f, 0.f, 0.f};
#pragma unroll
  for (int k = 0; k < 64; k += 4) {
    float4 v = *(const float4*)(src + k);
#pragma unroll
    for (int o = 0; o < 12; ++o) {
      float4 wv = *(const float4*)(&wl[o * 256 + q * 64 + k]);
      acc[o] += v.x * wv.x + v.y * wv.y + v.z * wv.z + v.w * wv.w;
    }
  }
#pragma unroll
  for (int o = 0; o < 12; ++o) {
    acc[o] += __shfl_xor(acc[o], 1);
    acc[o] += __shfl_xor(acc[o], 2);
  }
  if (q == 0) {
#pragma unroll
    for (int o = 0; o < 12; ++o)
      out[((size_t)b * 12 + o) * NODES + nOut] = acc[o] + b_reg[o];
  }
}

// ---------------- host ----------------
extern "C" void kernel_launch(void* const* d_in, const int* in_sizes, int n_in,
                              void* d_out, int out_size, void* d_ws, size_t ws_size,
                              hipStream_t stream) {
  (void)in_sizes; (void)n_in; (void)out_size;
  const float* x = (const float*)d_in[0];
  const int* te = (const int*)d_in[1];
  const int* reo_all = (const int*)d_in[2];
  const int* ori_parts = (const int*)d_in[3];
  const int* reo_parts = (const int*)d_in[4];
  const float* w_st = (const float*)d_in[5];
  const float* b_st = (const float*)d_in[6];
  const float* node_emb = (const float*)d_in[7];
  const float* tod_emb = (const float*)d_in[8];
  const float* dow_emb = (const float*)d_in[9];
  const float* s_qkv_w = (const float*)d_in[10];
  const float* s_qkv_b = (const float*)d_in[11];
  const float* s_proj_w = (const float*)d_in[12];
  const float* s_proj_b = (const float*)d_in[13];
  const float* s_fc1_w = (const float*)d_in[14];
  const float* s_fc1_b = (const float*)d_in[15];
  const float* s_fc2_w = (const float*)d_in[16];
  const float* s_fc2_b = (const float*)d_in[17];
  const float* n_qkv_w = (const float*)d_in[18];
  const float* n_qkv_b = (const float*)d_in[19];
  const float* n_proj_w = (const float*)d_in[20];
  const float* n_proj_b = (const float*)d_in[21];
  const float* n_fc1_w = (const float*)d_in[22];
  const float* n_fc1_b = (const float*)d_in[23];
  const float* n_fc2_w = (const float*)d_in[24];
  const float* n_fc2_b = (const float*)d_in[25];
  const float* w_reg = (const float*)d_in[26];
  const float* b_reg = (const float*)d_in[27];
  (void)reo_all;

  const size_t REX_BYTES = (size_t)NB * TPN * NODES * D * 4;  // 134217728
  if (ws_size < REX_BYTES + 1179648) return;
  float* rex = (float*)d_ws;
  u16* wt = (u16*)((char*)d_ws + REX_BYTES);
  u16* s_qkv_t = wt + 0;
  u16* s_prj_t = wt + 147456;
  u16* s_fc1_t = wt + 196608;
  u16* s_fc2_t = wt + 245760;
  u16* n_qkv_t = wt + 294912;
  u16* n_prj_t = wt + 442368;
  u16* n_fc1_t = wt + 491520;
  u16* n_fc2_t = wt + 540672;

  k_prep<<<(3 * 128 * 384 + 255) / 256, 256, 0, stream>>>(s_qkv_w, s_qkv_t, 128, 384);
  k_prep<<<(3 * 128 * 128 + 255) / 256, 256, 0, stream>>>(s_proj_w, s_prj_t, 128, 128);
  k_prep<<<(3 * 128 * 128 + 255) / 256, 256, 0, stream>>>(s_fc1_w, s_fc1_t, 128, 128);
  k_prep<<<(3 * 128 * 128 + 255) / 256, 256, 0, stream>>>(s_fc2_w, s_fc2_t, 128, 128);
  k_prep<<<(3 * 128 * 384 + 255) / 256, 256, 0, stream>>>(n_qkv_w, n_qkv_t, 128, 384);
  k_prep<<<(3 * 128 * 128 + 255) / 256, 256, 0, stream>>>(n_proj_w, n_prj_t, 128, 128);
  k_prep<<<(3 * 128 * 128 + 255) / 256, 256, 0, stream>>>(n_fc1_w, n_fc1_t, 128, 128);
  k_prep<<<(3 * 128 * 128 + 255) / 256, 256, 0, stream>>>(n_fc2_w, n_fc2_t, 128, 128);

  k_embed<<<NB * TPN * (NODES / 16), 256, 0, stream>>>(
      x, te, reo_parts, w_st, b_st, node_emb, tod_emb, dow_emb, rex);

  for (int l = 0; l < 3; ++l) {
    k_spatial_mlp<<<NB * TPN * P, 128, 0, stream>>>(
        rex, s_qkv_t + (size_t)l * 49152, s_qkv_b + l * 384,
        s_prj_t + (size_t)l * 16384, s_proj_b + l * 128,
        s_fc1_t + (size_t)l * 16384, s_fc1_b + l * 128,
        s_fc2_t + (size_t)l * 16384, s_fc2_b + l * 128);
    k_cross_mlp<<<NB * TPN * NPS, 1024, 0, stream>>>(
        rex, n_qkv_t + (size_t)l * 49152, n_qkv_b + l * 384,
        n_prj_t + (size_t)l * 16384, n_proj_b + l * 128,
        n_fc1_t + (size_t)l * 16384, n_fc1_b + l * 128,
        n_fc2_t + (size_t)l * 16384, n_fc2_b + l * 128);
  }

  k_readout<<<NB * (NODES / 64), 256, 0, stream>>>(
      rex, ori_parts, reo_parts, w_reg, b_reg, (float*)d_out);
}

// Round 6
// 2117.056 us; speedup vs baseline: 1.6007x; 1.1457x over previous
//
#include <hip/hip_runtime.h>

#define DEV __device__ __forceinline__
typedef __attribute__((ext_vector_type(8))) short s16x8;
typedef __attribute__((ext_vector_type(4))) float f32x4;
typedef unsigned short u16;

// ---------- constants ----------
#define NB 16      // B
#define TPN 2
#define NODES 8192
#define D 128
#define P 256
#define NPS 32
#define OUT_LEN 12

DEV f32x4 mfma16(s16x8 a, s16x8 b, f32x4 c) {
  return __builtin_amdgcn_mfma_f32_16x16x32_bf16(a, b, c, 0, 0, 0);
}

DEV short f2bf(float f) {
  union { float f; unsigned u; } v; v.f = f;
  unsigned r = v.u + 0x7fffu + ((v.u >> 16) & 1u);
  return (short)(r >> 16);
}

// swizzled LDS addressing: 256B-row and 512B-row buffers, XOR bits 4-6 by row&7
DEV int swz256(int row, int b) { return (row << 8) + (b ^ ((row & 7) << 4)); }
DEV int swz512(int row, int b) { return (row << 9) + (b ^ ((row & 7) << 4)); }

// A-fragment load: lane l -> row = mbase+(l&15), k = kbase+(l>>4)*8 .. +8
DEV s16x8 ldsA(const char* base, int mbase, int kbase, int lane) {
  int row = mbase + (lane & 15);
  int b = (kbase + ((lane >> 4) << 3)) << 1;
  return *(const s16x8*)(base + swz256(row, b));
}

// butterfly reduce across lane bits 0..3 (16-lane row groups)
DEV float rowred(float v) {
  v += __shfl_xor(v, 1);
  v += __shfl_xor(v, 2);
  v += __shfl_xor(v, 4);
  v += __shfl_xor(v, 8);
  return v;
}
DEV float rowmax(float v) {
  v = fmaxf(v, __shfl_xor(v, 1));
  v = fmaxf(v, __shfl_xor(v, 2));
  v = fmaxf(v, __shfl_xor(v, 4));
  v = fmaxf(v, __shfl_xor(v, 8));
  return v;
}
// reduce across g-groups (lane bits 4,5): full 128-col row sum for A-layout
DEV float gred(float v) {
  v += __shfl_xor(v, 16);
  v += __shfl_xor(v, 32);
  return v;
}

// stage one 64-col x 128-k bf16 weight tile (16KB) into LDS, swz256 layout.
DEV void stageW(char* buf, const u16* __restrict__ w, int tid) {
  int col = tid >> 4, kc = tid & 15;
  s16x8 v = *(const s16x8*)(w + col * 128 + kc * 8);
  *(s16x8*)(buf + swz256(col, kc * 16)) = v;
}

// ---------------- weight prep: f32 [3][K][N] -> bf16 [3][N][K] ----------------
__global__ void k_prep(const float* __restrict__ src, u16* __restrict__ dst, int K, int N) {
  int idx = blockIdx.x * 256 + threadIdx.x;
  int total = 3 * K * N;
  if (idx >= total) return;
  int l = idx / (K * N);
  int r = idx - l * K * N;
  int n = r / K;
  int k = r - n * K;
  dst[idx] = (u16)f2bf(src[l * K * N + k * N + n]);
}

// ---------------- embedding (scatter form) ----------------
__global__ __launch_bounds__(256) void k_embed(
    const float* __restrict__ x, const int* __restrict__ te, const int* __restrict__ reo_parts,
    const float* __restrict__ w_st, const float* __restrict__ b_st,
    const float* __restrict__ node_emb, const float* __restrict__ tod_emb,
    const float* __restrict__ dow_emb, float* __restrict__ rex) {
  __shared__ float sx[12][16], s0[12][16], s1[12][16];
  __shared__ int sed[2][16];
  __shared__ int sj[16];
  __shared__ float hb[16][132];
  int gid = blockIdx.x;
  int chunk = gid & 511, bt = gid >> 9;
  int b = bt >> 1, tt = bt & 1;
  int tid = threadIdx.x;
  int nl = tid & 15, c = tid >> 4;
  int n = chunk * 16 + nl;
  if (c < 12) {
    size_t off = ((size_t)(b * 24 + tt * 12 + c)) * NODES + n;
    sx[c][nl] = x[off];
    int2 t2 = *(const int2*)(te + 2 * off);
    s0[c][nl] = (float)t2.x * (1.0f / 288.0f);
    s1[c][nl] = (float)t2.y * (1.0f / 7.0f);
  } else if (c == 12) {
    size_t off = ((size_t)(b * 24 + 22 + tt)) * NODES + n;
    int2 t2 = *(const int2*)(te + 2 * off);
    sed[0][nl] = t2.x;
    sed[1][nl] = t2.y;
  } else if (c == 13) {
    sj[nl] = reo_parts[n];
  }
  __syncthreads();
  int db = c * 8;
  float o[8];
#pragma unroll
  for (int dd = 0; dd < 8; ++dd) {
    int d = db + dd;
    float v;
    if (d < 64) {
      float acc = b_st[d];
      const float* wd = w_st + d * 36;
#pragma unroll
      for (int p = 0; p < 12; ++p)
        acc += sx[p][nl] * wd[p] + s0[p][nl] * wd[12 + p] + s1[p][nl] * wd[24 + p];
      v = acc;
    } else if (d < 80) {
      v = tod_emb[sed[0][nl] * 16 + (d - 64)];
    } else if (d < 96) {
      v = dow_emb[sed[1][nl] * 16 + (d - 80)];
    } else {
      v = node_emb[n * 32 + (d - 96)];
    }
    o[dd] = v;
  }
  *(float4*)&hb[nl][db] = make_float4(o[0], o[1], o[2], o[3]);
  *(float4*)&hb[nl][db + 4] = make_float4(o[4], o[5], o[6], o[7]);
  __syncthreads();
  int row = tid >> 4, cw = tid & 15;
  float4 v0 = *(float4*)&hb[row][cw * 8];
  float4 v1 = *(float4*)&hb[row][cw * 8 + 4];
  float* dst = rex + ((size_t)bt * NODES + sj[row]) * D + cw * 8;
  *(float4*)dst = v0;
  *(float4*)(dst + 4) = v1;
}

// ---------------- fused transformer sublayer pair: 16 waves, 256 tokens, staged weights ----
// CROSS=true : token stride 4096 (cross-patch sequences), full-256 attention (2-pass softmax)
// CROSS=false: token stride 128 (contiguous patch tokens), per-patch 32-token attention
// LDS map (160 KiB): Kb[0,64K) K rows | VT[64K,128K) V^T | WS[128K,160K) weight dbuf.
// Aliases: scrQ (pre-V) in VT region, scrO (post-attn) in Kb region, Pscr in WS region.
template <bool CROSS>
__global__ __launch_bounds__(1024, 4) void k_fused(
    float* __restrict__ rex,
    const u16* __restrict__ wqkv, const float* __restrict__ bqkv,
    const u16* __restrict__ wprj, const float* __restrict__ bprj,
    const u16* __restrict__ w1t, const float* __restrict__ b1,
    const u16* __restrict__ w2t, const float* __restrict__ b2) {
  __shared__ __align__(16) char sm[163840];
  char* Kb = sm;
  char* VT = sm + 65536;
  char* WSa = sm + 131072;
  char* WSb = sm + 147456;
  int tid = threadIdx.x;
  int w = tid >> 6, lane = tid & 63;
  int r = lane & 15, g = lane >> 4;
  char* scrQ = sm + 65536 + w * 4096;
  char* scrO = sm + w * 4096;
  char* Pscr = sm + 131072 + w * 1280;

  int sq = blockIdx.x;
  const int TS = CROSS ? (NPS * D) : D;  // token stride in floats
  float* Xrow;
  if (CROSS) {
    int bt = sq >> 5, i = sq & 31;
    Xrow = rex + (size_t)bt * (NODES * D) + i * D + (size_t)(w * 16 + r) * TS;
  } else {
    Xrow = rex + (size_t)sq * (256 * D) + (size_t)(w * 16 + r) * TS;
  }

  // ---- A-layout load: xr[kt][j] = X[row][kt*32 + g*8 + j]
  float xr[4][8];
#pragma unroll
  for (int kt = 0; kt < 4; ++kt) {
    float4 a = *(const float4*)(Xrow + kt * 32 + g * 8);
    float4 b = *(const float4*)(Xrow + kt * 32 + g * 8 + 4);
    xr[kt][0] = a.x; xr[kt][1] = a.y; xr[kt][2] = a.z; xr[kt][3] = a.w;
    xr[kt][4] = b.x; xr[kt][5] = b.y; xr[kt][6] = b.z; xr[kt][7] = b.w;
  }

  // ---- LN1 fully in-register
  s16x8 ax[4];
  {
    float s = 0.f, s2 = 0.f;
#pragma unroll
    for (int kt = 0; kt < 4; ++kt)
#pragma unroll
      for (int j = 0; j < 8; ++j) { float v = xr[kt][j]; s += v; s2 += v * v; }
    s = gred(s); s2 = gred(s2);
    float m = s * 0.0078125f;
    float rsd = rsqrtf(s2 * 0.0078125f - m * m + 1e-6f);
#pragma unroll
    for (int kt = 0; kt < 4; ++kt) {
      s16x8 o;
#pragma unroll
      for (int j = 0; j < 8; ++j) o[j] = f2bf((xr[kt][j] - m) * rsd);
      ax[kt] = o;
    }
  }

  // ---- QKV: 6 staged 64-col tiles (Q:0-1 -> scrQ, K:2-3 -> Kb, V:4-5 -> VT)
  stageW(WSa, wqkv, tid);
  __syncthreads();
  s16x8 aq[4];
  for (int t = 0; t < 6; ++t) {
    const char* cur = (t & 1) ? WSb : WSa;
    if (t < 5) stageW((t & 1) ? WSa : WSb, wqkv + (size_t)(t + 1) * 8192, tid);
#pragma unroll
    for (int sub = 0; sub < 4; ++sub) {
      int colg = t * 64 + sub * 16 + r;
      f32x4 acc = {0.f, 0.f, 0.f, 0.f};
#pragma unroll
      for (int kt = 0; kt < 4; ++kt)
        acc = mfma16(ax[kt], ldsA(cur, sub * 16, kt * 32, lane), acc);
      float bias = bqkv[colg];
#pragma unroll
      for (int e = 0; e < 4; ++e) {
        float v = acc[e] + bias;
        int tok = w * 16 + g * 4 + e;
        if (t < 2) {
          *(u16*)(scrQ + swz256(g * 4 + e, colg * 2)) = (u16)f2bf(v);
        } else if (t < 4) {
          *(u16*)(Kb + swz256(tok, (colg - 128) * 2)) = (u16)f2bf(v);
        } else {
          *(u16*)(VT + swz512(colg - 256, tok * 2)) = (u16)f2bf(v);
        }
      }
    }
    if (t == 1) {
#pragma unroll
      for (int kt = 0; kt < 4; ++kt) aq[kt] = ldsA(scrQ, 0, kt * 32, lane);
    }
    __syncthreads();
  }

  const float scale = 0.08838834764831845f;
  float sum[4];
  f32x4 av[8];

  if (CROSS) {
    // ---- pass 1: raw-score row max over all 256 keys
    float mx[4] = {-3.0e38f, -3.0e38f, -3.0e38f, -3.0e38f};
#pragma unroll 2
    for (int kt2 = 0; kt2 < 16; ++kt2) {
      f32x4 acc = {0.f, 0.f, 0.f, 0.f};
#pragma unroll
      for (int kt = 0; kt < 4; ++kt) {
        s16x8 b = ldsA(Kb, kt2 * 16, kt * 32, lane);
        acc = mfma16(aq[kt], b, acc);
      }
#pragma unroll
      for (int e = 0; e < 4; ++e) mx[e] = fmaxf(mx[e], acc[e]);
    }
#pragma unroll
    for (int e = 0; e < 4; ++e) mx[e] = rowmax(mx[e]);

    // ---- pass 2: recompute, exp, stage P tile, AV accumulate
#pragma unroll
    for (int e = 0; e < 4; ++e) sum[e] = 0.f;
#pragma unroll
    for (int nt = 0; nt < 8; ++nt) av[nt] = (f32x4){0.f, 0.f, 0.f, 0.f};
    for (int cc = 0; cc < 8; ++cc) {
#pragma unroll
      for (int sub = 0; sub < 2; ++sub) {
        int kt2 = cc * 2 + sub;
        f32x4 acc = {0.f, 0.f, 0.f, 0.f};
#pragma unroll
        for (int kt = 0; kt < 4; ++kt) {
          s16x8 b = ldsA(Kb, kt2 * 16, kt * 32, lane);
          acc = mfma16(aq[kt], b, acc);
        }
#pragma unroll
        for (int e = 0; e < 4; ++e) {
          float p = __expf((acc[e] - mx[e]) * scale);
          sum[e] += p;
          *(u16*)(Pscr + (g * 4 + e) * 80 + (sub * 16 + r) * 2) = (u16)f2bf(p);
        }
      }
      s16x8 ap = *(const s16x8*)(Pscr + r * 80 + g * 16);
#pragma unroll
      for (int nt = 0; nt < 8; ++nt) {
        s16x8 bv = *(const s16x8*)(VT + swz512(nt * 16 + r, (cc * 32 + g * 8) * 2));
        av[nt] = mfma16(ap, bv, av[nt]);
      }
    }
#pragma unroll
    for (int e = 0; e < 4; ++e) sum[e] = rowred(sum[e]);
  } else {
    // ---- per-patch attention (32 keys), scores kept in registers
    int pw = w >> 1;  // patch of this wave (2 waves per patch)
    f32x4 sc[2];
#pragma unroll
    for (int sub = 0; sub < 2; ++sub) {
      f32x4 acc = {0.f, 0.f, 0.f, 0.f};
#pragma unroll
      for (int kt = 0; kt < 4; ++kt) {
        s16x8 b = ldsA(Kb, (pw * 2 + sub) * 16, kt * 32, lane);
        acc = mfma16(aq[kt], b, acc);
      }
      sc[sub] = acc;
    }
#pragma unroll
    for (int e = 0; e < 4; ++e) {
      float m = fmaxf(sc[0][e], sc[1][e]);
      m = rowmax(m);
      float p0 = __expf((sc[0][e] - m) * scale);
      float p1 = __expf((sc[1][e] - m) * scale);
      sum[e] = rowred(p0 + p1);
      *(u16*)(Pscr + (g * 4 + e) * 80 + r * 2) = (u16)f2bf(p0);
      *(u16*)(Pscr + (g * 4 + e) * 80 + (16 + r) * 2) = (u16)f2bf(p1);
    }
    s16x8 ap = *(const s16x8*)(Pscr + r * 80 + g * 16);
#pragma unroll
    for (int nt = 0; nt < 8; ++nt) {
      s16x8 bv = *(const s16x8*)(VT + swz512(nt * 16 + r, (pw * 32 + g * 8) * 2));
      f32x4 z = {0.f, 0.f, 0.f, 0.f};
      av[nt] = mfma16(ap, bv, z);
    }
  }
  __syncthreads();  // Kb/VT reads done -> scrO & WS reusable

  // ---- normalize AV -> scrO (bf16) -> aav
  {
    float rinv[4];
#pragma unroll
    for (int e = 0; e < 4; ++e) rinv[e] = 1.0f / sum[e];
#pragma unroll
    for (int nt = 0; nt < 8; ++nt)
#pragma unroll
      for (int e = 0; e < 4; ++e)
        *(u16*)(scrO + swz256(g * 4 + e, (nt * 16 + r) * 2)) = (u16)f2bf(av[nt][e] * rinv[e]);
  }
  s16x8 aav[4];
#pragma unroll
  for (int kt = 0; kt < 4; ++kt) aav[kt] = ldsA(scrO, 0, kt * 32, lane);

  // ---- proj: 2 staged tiles, C-out -> f32 bounce -> xr (A-layout)
  stageW(WSa, wprj, tid);
  __syncthreads();
#pragma unroll
  for (int t = 0; t < 2; ++t) {
    const char* cur = t ? WSb : WSa;
    if (t == 0) stageW(WSb, wprj + 8192, tid);
#pragma unroll
    for (int sub = 0; sub < 4; ++sub) {
      int colg = t * 64 + sub * 16 + r;
      f32x4 acc = {0.f, 0.f, 0.f, 0.f};
#pragma unroll
      for (int kt = 0; kt < 4; ++kt)
        acc = mfma16(aav[kt], ldsA(cur, sub * 16, kt * 32, lane), acc);
      float bias = bprj[colg];
#pragma unroll
      for (int e = 0; e < 4; ++e) {
        int row = g * 4 + e;
        *(float*)(scrO + row * 256 + (((sub * 16 + r) * 4) ^ ((row & 7) << 4))) = acc[e] + bias;
      }
    }
#pragma unroll
    for (int kk = 0; kk < 2; ++kk) {
      int base = kk * 128 + g * 32;
      f32x4 u0 = *(const f32x4*)(scrO + r * 256 + (base ^ ((r & 7) << 4)));
      f32x4 u1 = *(const f32x4*)(scrO + r * 256 + ((base + 16) ^ ((r & 7) << 4)));
      int kt = t * 2 + kk;
      xr[kt][0] += u0[0]; xr[kt][1] += u0[1]; xr[kt][2] += u0[2]; xr[kt][3] += u0[3];
      xr[kt][4] += u1[0]; xr[kt][5] += u1[1]; xr[kt][6] += u1[2]; xr[kt][7] += u1[3];
    }
    __syncthreads();
  }

  // ---- LN2 in-register
  s16x8 ah[4];
  {
    float s = 0.f, s2 = 0.f;
#pragma unroll
    for (int kt = 0; kt < 4; ++kt)
#pragma unroll
      for (int j = 0; j < 8; ++j) { float v = xr[kt][j]; s += v; s2 += v * v; }
    s = gred(s); s2 = gred(s2);
    float m = s * 0.0078125f;
    float rsd = rsqrtf(s2 * 0.0078125f - m * m + 1e-6f);
#pragma unroll
    for (int kt = 0; kt < 4; ++kt) {
      s16x8 o;
#pragma unroll
      for (int j = 0; j < 8; ++j) o[j] = f2bf((xr[kt][j] - m) * rsd);
      ah[kt] = o;
    }
  }

  // ---- fc1 + gelu -> scrO bf16
  stageW(WSa, w1t, tid);
  __syncthreads();
  s16x8 ah2[4];
#pragma unroll
  for (int t = 0; t < 2; ++t) {
    const char* cur = t ? WSb : WSa;
    if (t == 0) stageW(WSb, w1t + 8192, tid);
#pragma unroll
    for (int sub = 0; sub < 4; ++sub) {
      int colg = t * 64 + sub * 16 + r;
      f32x4 acc = {0.f, 0.f, 0.f, 0.f};
#pragma unroll
      for (int kt = 0; kt < 4; ++kt)
        acc = mfma16(ah[kt], ldsA(cur, sub * 16, kt * 32, lane), acc);
      float bias = b1[colg];
#pragma unroll
      for (int e = 0; e < 4; ++e) {
        float v0 = acc[e] + bias;
        v0 = 0.5f * v0 * (1.0f + erff(v0 * 0.70710678118654752f));
        *(u16*)(scrO + swz256(g * 4 + e, colg * 2)) = (u16)f2bf(v0);
      }
    }
    if (t == 1) {
#pragma unroll
      for (int kt = 0; kt < 4; ++kt) ah2[kt] = ldsA(scrO, 0, kt * 32, lane);
    }
    __syncthreads();
  }

  // ---- fc2: 2 staged tiles, C-out -> f32 bounce -> xr
  stageW(WSa, w2t, tid);
  __syncthreads();
#pragma unroll
  for (int t = 0; t < 2; ++t) {
    const char* cur = t ? WSb : WSa;
    if (t == 0) stageW(WSb, w2t + 8192, tid);
#pragma unroll
    for (int sub = 0; sub < 4; ++sub) {
      int colg = t * 64 + sub * 16 + r;
      f32x4 acc = {0.f, 0.f, 0.f, 0.f};
#pragma unroll
      for (int kt = 0; kt < 4; ++kt)
        acc = mfma16(ah2[kt], ldsA(cur, sub * 16, kt * 32, lane), acc);
      float bias = b2[colg];
#pragma unroll
      for (int e = 0; e < 4; ++e) {
        int row = g * 4 + e;
        *(float*)(scrO + row * 256 + (((sub * 16 + r) * 4) ^ ((row & 7) << 4))) = acc[e] + bias;
      }
    }
#pragma unroll
    for (int kk = 0; kk < 2; ++kk) {
      int base = kk * 128 + g * 32;
      f32x4 u0 = *(const f32x4*)(scrO + r * 256 + (base ^ ((r & 7) << 4)));
      f32x4 u1 = *(const f32x4*)(scrO + r * 256 + ((base + 16) ^ ((r & 7) << 4)));
      int kt = t * 2 + kk;
      xr[kt][0] += u0[0]; xr[kt][1] += u0[1]; xr[kt][2] += u0[2]; xr[kt][3] += u0[3];
      xr[kt][4] += u1[0]; xr[kt][5] += u1[1]; xr[kt][6] += u1[2]; xr[kt][7] += u1[3];
    }
    if (t == 0) __syncthreads();
  }

  // ---- store (32B vector stores)
#pragma unroll
  for (int kt = 0; kt < 4; ++kt) {
    *(float4*)(Xrow + kt * 32 + g * 8) =
        make_float4(xr[kt][0], xr[kt][1], xr[kt][2], xr[kt][3]);
    *(float4*)(Xrow + kt * 32 + g * 8 + 4) =
        make_float4(xr[kt][4], xr[kt][5], xr[kt][6], xr[kt][7]);
  }
}

// ---------------- readout ----------------
__global__ __launch_bounds__(256) void k_readout(
    const float* __restrict__ rex, const int* __restrict__ ori_idx,
    const int* __restrict__ reo_idx, const float* __restrict__ w_reg,
    const float* __restrict__ b_reg, float* __restrict__ out) {
  __shared__ float wl[3072];
  for (int i2 = threadIdx.x; i2 < 3072; i2 += 256) wl[i2] = w_reg[i2];
  __syncthreads();
  int b = blockIdx.x >> 7;
  int chunk = blockIdx.x & 127;
  int m = chunk * 64 + (threadIdx.x >> 2);
  int q = threadIdx.x & 3;
  int nOut = ori_idx[m];
  int j = reo_idx[m];
  int t = q >> 1;
  const float* src = rex + ((size_t)(b * 2 + t) * NODES + j) * D + (q & 1) * 64;
  float acc[12] = {0.f, 0.f, 0.f, 0.f, 0.f, 0.f, 0.f, 0.f, 0.f, 0.f, 0.f, 0.f};
#pragma unroll
  for (int k = 0; k < 64; k += 4) {
    float4 v = *(const float4*)(src + k);
#pragma unroll
    for (int o = 0; o < 12; ++o) {
      float4 wv = *(const float4*)(&wl[o * 256 + q * 64 + k]);
      acc[o] += v.x * wv.x + v.y * wv.y + v.z * wv.z + v.w * wv.w;
    }
  }
#pragma unroll
  for (int o = 0; o < 12; ++o) {
    acc[o] += __shfl_xor(acc[o], 1);
    acc[o] += __shfl_xor(acc[o], 2);
  }
  if (q == 0) {
#pragma unroll
    for (int o = 0; o < 12; ++o)
      out[((size_t)b * 12 + o) * NODES + nOut] = acc[o] + b_reg[o];
  }
}

// ---------------- host ----------------
extern "C" void kernel_launch(void* const* d_in, const int* in_sizes, int n_in,
                              void* d_out, int out_size, void* d_ws, size_t ws_size,
                              hipStream_t stream) {
  (void)in_sizes; (void)n_in; (void)out_size;
  const float* x = (const float*)d_in[0];
  const int* te = (const int*)d_in[1];
  const int* reo_all = (const int*)d_in[2];
  const int* ori_parts = (const int*)d_in[3];
  const int* reo_parts = (const int*)d_in[4];
  const float* w_st = (const float*)d_in[5];
  const float* b_st = (const float*)d_in[6];
  const float* node_emb = (const float*)d_in[7];
  const float* tod_emb = (const float*)d_in[8];
  const float* dow_emb = (const float*)d_in[9];
  const float* s_qkv_w = (const float*)d_in[10];
  const float* s_qkv_b = (const float*)d_in[11];
  const float* s_proj_w = (const float*)d_in[12];
  const float* s_proj_b = (const float*)d_in[13];
  const float* s_fc1_w = (const float*)d_in[14];
  const float* s_fc1_b = (const float*)d_in[15];
  const float* s_fc2_w = (const float*)d_in[16];
  const float* s_fc2_b = (const float*)d_in[17];
  const float* n_qkv_w = (const float*)d_in[18];
  const float* n_qkv_b = (const float*)d_in[19];
  const float* n_proj_w = (const float*)d_in[20];
  const float* n_proj_b = (const float*)d_in[21];
  const float* n_fc1_w = (const float*)d_in[22];
  const float* n_fc1_b = (const float*)d_in[23];
  const float* n_fc2_w = (const float*)d_in[24];
  const float* n_fc2_b = (const float*)d_in[25];
  const float* w_reg = (const float*)d_in[26];
  const float* b_reg = (const float*)d_in[27];
  (void)reo_all;

  const size_t REX_BYTES = (size_t)NB * TPN * NODES * D * 4;  // 134217728
  if (ws_size < REX_BYTES + 1179648) return;
  float* rex = (float*)d_ws;
  u16* wt = (u16*)((char*)d_ws + REX_BYTES);
  u16* s_qkv_t = wt + 0;
  u16* s_prj_t = wt + 147456;
  u16* s_fc1_t = wt + 196608;
  u16* s_fc2_t = wt + 245760;
  u16* n_qkv_t = wt + 294912;
  u16* n_prj_t = wt + 442368;
  u16* n_fc1_t = wt + 491520;
  u16* n_fc2_t = wt + 540672;

  k_prep<<<(3 * 128 * 384 + 255) / 256, 256, 0, stream>>>(s_qkv_w, s_qkv_t, 128, 384);
  k_prep<<<(3 * 128 * 128 + 255) / 256, 256, 0, stream>>>(s_proj_w, s_prj_t, 128, 128);
  k_prep<<<(3 * 128 * 128 + 255) / 256, 256, 0, stream>>>(s_fc1_w, s_fc1_t, 128, 128);
  k_prep<<<(3 * 128 * 128 + 255) / 256, 256, 0, stream>>>(s_fc2_w, s_fc2_t, 128, 128);
  k_prep<<<(3 * 128 * 384 + 255) / 256, 256, 0, stream>>>(n_qkv_w, n_qkv_t, 128, 384);
  k_prep<<<(3 * 128 * 128 + 255) / 256, 256, 0, stream>>>(n_proj_w, n_prj_t, 128, 128);
  k_prep<<<(3 * 128 * 128 + 255) / 256, 256, 0, stream>>>(n_fc1_w, n_fc1_t, 128, 128);
  k_prep<<<(3 * 128 * 128 + 255) / 256, 256, 0, stream>>>(n_fc2_w, n_fc2_t, 128, 128);

  k_embed<<<NB * TPN * (NODES / 16), 256, 0, stream>>>(
      x, te, reo_parts, w_st, b_st, node_emb, tod_emb, dow_emb, rex);

  for (int l = 0; l < 3; ++l) {
    k_fused<false><<<NB * TPN * (NODES / 256), 1024, 0, stream>>>(
        rex, s_qkv_t + (size_t)l * 49152, s_qkv_b + l * 384,
        s_prj_t + (size_t)l * 16384, s_proj_b + l * 128,
        s_fc1_t + (size_t)l * 16384, s_fc1_b + l * 128,
        s_fc2_t + (size_t)l * 16384, s_fc2_b + l * 128);
    k_fused<true><<<NB * TPN * NPS, 1024, 0, stream>>>(
        rex, n_qkv_t + (size_t)l * 49152, n_qkv_b + l * 384,
        n_prj_t + (size_t)l * 16384, n_proj_b + l * 128,
        n_fc1_t + (size_t)l * 16384, n_fc1_b + l * 128,
        n_fc2_t + (size_t)l * 16384, n_fc2_b + l * 128);
  }

  k_readout<<<NB * (NODES / 64), 256, 0, stream>>>(
      rex, ori_parts, reo_parts, w_reg, b_reg, (float*)d_out);
}